// Round 2
// baseline (1227.177 us; speedup 1.0000x reference)
//
#include <hip/hip_runtime.h>
#include <hip/hip_bf16.h>
#include <cmath>

typedef unsigned short u16;
typedef unsigned int u32;

using bf16x8 = __attribute__((ext_vector_type(8))) short;
using f32x4  = __attribute__((ext_vector_type(4))) float;

__device__ __forceinline__ float b2f(u16 u) {
  union { u32 i; float f; } x; x.i = ((u32)u) << 16; return x.f;
}
__device__ __forceinline__ u16 f2b(float f) {
  union { float f; u32 i; } x; x.f = f;
  u32 r = x.i + 0x7fffu + ((x.i >> 16) & 1u);
  return (u16)(r >> 16);
}

// ---------------- weight cast fp32 -> bf16 ----------------
__global__ __launch_bounds__(256) void castw(const float* __restrict__ a,
                                             u16* __restrict__ o, int n) {
  int i = blockIdx.x * 256 + threadIdx.x;
  if (i < n) o[i] = f2b(a[i]);
}

// ---------------- LayerNorm (+ optional roll+window-partition gather) ------
__global__ __launch_bounds__(256) void ln_k(const float* __restrict__ src,
                                            const float* __restrict__ g,
                                            const float* __restrict__ b,
                                            u16* __restrict__ dst, int shifted) {
  const int wid = threadIdx.x >> 6, lane = threadIdx.x & 63;
  const int row = blockIdx.x * 4 + wid;
  int srow;
  if (shifted) {
    int widx = row / 392, n = row - widx * 392;
    int wt = widx >> 6, wh = (widx >> 3) & 7, ww = widx & 7;
    int ti = n / 49, rem = n - ti * 49, hi = rem / 7, wi = rem - hi * 7;
    int t = (wt * 8 + ti + 4) & 15;
    int h = wh * 7 + hi + 3; if (h >= 56) h -= 56;
    int w = ww * 7 + wi + 3; if (w >= 56) w -= 56;
    srow = (t * 56 + h) * 56 + w;
  } else {
    srow = row;
  }
  float4 v = *(const float4*)(src + (size_t)srow * 256 + lane * 4);
  float s = v.x + v.y + v.z + v.w;
  float sq = v.x * v.x + v.y * v.y + v.z * v.z + v.w * v.w;
  for (int o = 1; o < 64; o <<= 1) {
    s += __shfl_xor(s, o, 64);
    sq += __shfl_xor(sq, o, 64);
  }
  float mu = s * (1.0f / 256.0f);
  float rstd = rsqrtf(sq * (1.0f / 256.0f) - mu * mu + 1e-5f);
  float4 gg = *(const float4*)(g + lane * 4);
  float4 bb = *(const float4*)(b + lane * 4);
  ushort4 ov;
  ov.x = f2b((v.x - mu) * rstd * gg.x + bb.x);
  ov.y = f2b((v.y - mu) * rstd * gg.y + bb.y);
  ov.z = f2b((v.z - mu) * rstd * gg.z + bb.z);
  ov.w = f2b((v.w - mu) * rstd * gg.w + bb.w);
  *(ushort4*)(dst + (size_t)row * 256 + lane * 4) = ov;
}

// ---------------- MFMA GEMM: C = A(MxK) @ B(NxK)^T, templated epilogue -----
template <int EPI>
__global__ __launch_bounds__(256) void gemm_k(const u16* __restrict__ A,
                                              const u16* __restrict__ Bw, int K,
                                              int tilesN,
                                              const float* __restrict__ bias,
                                              u16* __restrict__ outb,
                                              float* __restrict__ outf,
                                              const float* __restrict__ res,
                                              float qscale) {
  __shared__ __align__(16) u16 As[128][40];
  __shared__ __align__(16) u16 Bs[128][40];
  const int tid = threadIdx.x;
  const int tm = blockIdx.x / tilesN, tn = blockIdx.x % tilesN;
  const int wid = tid >> 6, lane = tid & 63;
  const int wm = wid >> 1, wn = wid & 1;
  const int lm = lane & 15, lk = lane >> 4;
  f32x4 acc[4][4] = {};
  const u16* Ap = A + (size_t)tm * 128 * K;
  const u16* Bp = Bw + (size_t)tn * 128 * K;
  const int r0 = tid >> 2, cg0 = (tid & 3) * 8;
  for (int k0 = 0; k0 < K; k0 += 32) {
    __syncthreads();
    *(bf16x8*)&As[r0][cg0]      = *(const bf16x8*)(Ap + (size_t)r0 * K + k0 + cg0);
    *(bf16x8*)&As[r0 + 64][cg0] = *(const bf16x8*)(Ap + (size_t)(r0 + 64) * K + k0 + cg0);
    *(bf16x8*)&Bs[r0][cg0]      = *(const bf16x8*)(Bp + (size_t)r0 * K + k0 + cg0);
    *(bf16x8*)&Bs[r0 + 64][cg0] = *(const bf16x8*)(Bp + (size_t)(r0 + 64) * K + k0 + cg0);
    __syncthreads();
    bf16x8 af[4], bfr[4];
#pragma unroll
    for (int f = 0; f < 4; f++) {
      af[f]  = *(const bf16x8*)&As[wm * 64 + f * 16 + lm][lk * 8];
      bfr[f] = *(const bf16x8*)&Bs[wn * 64 + f * 16 + lm][lk * 8];
    }
#pragma unroll
    for (int fm = 0; fm < 4; fm++)
#pragma unroll
      for (int fn = 0; fn < 4; fn++)
        acc[fm][fn] = __builtin_amdgcn_mfma_f32_16x16x32_bf16(
            af[fm], bfr[fn], acc[fm][fn], 0, 0, 0);
  }
  const int rbase = tm * 128 + wm * 64, cbase = tn * 128 + wn * 64;
#pragma unroll
  for (int fm = 0; fm < 4; fm++) {
#pragma unroll
    for (int fn = 0; fn < 4; fn++) {
      const int col = cbase + fn * 16 + lm;
#pragma unroll
      for (int r = 0; r < 4; r++) {
        const int row = rbase + fm * 16 + lk * 4 + r;
        float v = acc[fm][fn][r] + bias[col];
        if (EPI == 0) {
          int s = col >> 8, rem = col & 255, head = rem >> 5, d = rem & 31;
          if (s == 0) v *= qscale;
          int widx = row / 392, n = row - widx * 392;
          size_t o = (size_t)s * 12845056u +
                     (((size_t)(widx * 8 + head)) * 392 + n) * 32 + d;
          outb[o] = f2b(v);
        } else if (EPI == 1) {
          int widx = row / 392, n = row - widx * 392;
          int wt = widx >> 6, wh = (widx >> 3) & 7, ww = widx & 7;
          int ti = n / 49, rem2 = n - ti * 49, hi = rem2 / 7, wi = rem2 - hi * 7;
          int t = (wt * 8 + ti + 4) & 15;
          int h = wh * 7 + hi + 3; if (h >= 56) h -= 56;
          int w = ww * 7 + wi + 3; if (w >= 56) w -= 56;
          size_t dr = ((size_t)(t * 56 + h)) * 56 + w;
          outf[dr * 256 + col] = res[dr * 256 + col] + v;
        } else if (EPI == 2) {
          float gv = 0.5f * v * (1.0f + erff(v * 0.70710678f));
          outb[(size_t)row * 1024 + col] = f2b(gv);
        } else {
          outf[(size_t)row * 256 + col] = res[(size_t)row * 256 + col] + v;
        }
      }
    }
  }
}

// ---------------- windowed attention, one block per (window, head) --------
__global__ __launch_bounds__(256) void attn_k(const u16* __restrict__ qg,
                                              const u16* __restrict__ kg,
                                              const u16* __restrict__ vg,
                                              const float* __restrict__ rpb,
                                              u16* __restrict__ attno) {
  __shared__ __align__(16) u16 Ks[392][34];
  __shared__ __align__(16) u16 Vt[32][396];
  __shared__ __align__(16) float ps[4][392];
  __shared__ __align__(16) u16 rpbs[2535];
  __shared__ __align__(16) int cls[392];
  __shared__ __align__(16) float qrow[4][32];

  const int bid = blockIdx.x;  // widx*8 + head
  const int widx = bid >> 3, head = bid & 7;
  const int tid = threadIdx.x, wid = tid >> 6, lane = tid & 63;
  const size_t base = (size_t)bid * 12544;  // 392*32

  for (int idx = tid; idx < 392 * 16; idx += 256) {
    int j = idx >> 4, d2 = idx & 15;
    ushort2 kk = *(const ushort2*)(kg + base + j * 32 + d2 * 2);
    *(ushort2*)&Ks[j][d2 * 2] = kk;
  }
  for (int idx = tid; idx < 392 * 8; idx += 256) {
    int j = idx >> 3, d4 = idx & 7;
    ushort4 vv = *(const ushort4*)(vg + base + j * 32 + d4 * 4);
    Vt[d4 * 4 + 0][j] = vv.x;
    Vt[d4 * 4 + 1][j] = vv.y;
    Vt[d4 * 4 + 2][j] = vv.z;
    Vt[d4 * 4 + 3][j] = vv.w;
  }
  for (int i = tid; i < 2535; i += 256) rpbs[i] = f2b(rpb[i * 8 + head]);
  {
    int wt = widx >> 6, wh = (widx >> 3) & 7, ww = widx & 7;
    for (int i = tid; i < 392; i += 256) {
      int ti = i / 49, rem = i - ti * 49, hi = rem / 7, wi = rem - hi * 7;
      int c = ti * 169 + hi * 13 + wi;
      int at = wt * 8 + ti, ah = wh * 7 + hi, aw = ww * 7 + wi;
      int rt = (at < 8) ? 0 : ((at < 12) ? 1 : 2);
      int rh = (ah < 49) ? 0 : ((ah < 53) ? 1 : 2);
      int rw = (aw < 49) ? 0 : ((aw < 53) ? 1 : 2);
      cls[i] = c | ((rt * 9 + rh * 3 + rw) << 16);
    }
  }
  __syncthreads();

  for (int rb = 0; rb < 392; rb += 4) {
    if (tid < 128)
      qrow[tid >> 5][tid & 31] = b2f(qg[base + (size_t)(rb + (tid >> 5)) * 32 + (tid & 31)]);
    __syncthreads();
    const int row = rb + wid;  // always < 392 (392 = 4*98)
    const int cli = cls[row];
    const int ci = cli & 0xffff, li = cli >> 16;
    float sreg[7];
#pragma unroll
    for (int cc = 0; cc < 7; cc++) {
      int j = cc * 64 + lane;
      float s = -1e30f;
      if (j < 392) {
        s = 0.f;
#pragma unroll
        for (int d2 = 0; d2 < 16; d2++) {
          ushort2 kk = *(const ushort2*)&Ks[j][d2 * 2];
          s += qrow[wid][d2 * 2] * b2f(kk.x) + qrow[wid][d2 * 2 + 1] * b2f(kk.y);
        }
        int cj = cls[j];
        s += b2f(rpbs[ci - (cj & 0xffff) + 1267]);
        if (li != (cj >> 16)) s -= 100.f;
      }
      sreg[cc] = s;
    }
    float m = sreg[0];
#pragma unroll
    for (int cc = 1; cc < 7; cc++) m = fmaxf(m, sreg[cc]);
    for (int o = 1; o < 64; o <<= 1) m = fmaxf(m, __shfl_xor(m, o, 64));
    float sum = 0.f;
#pragma unroll
    for (int cc = 0; cc < 7; cc++) {
      int j = cc * 64 + lane;
      float e = (j < 392) ? __expf(sreg[cc] - m) : 0.f;
      sreg[cc] = e;
      sum += e;
    }
    for (int o = 1; o < 64; o <<= 1) sum += __shfl_xor(sum, o, 64);
    float inv = 1.f / sum;
#pragma unroll
    for (int cc = 0; cc < 7; cc++) {
      int j = cc * 64 + lane;
      if (j < 392) ps[wid][j] = sreg[cc] * inv;
    }
    // same-wave DS ordering: drain writes before cross-lane reads
    asm volatile("s_waitcnt lgkmcnt(0)" ::: "memory");
    const int d = lane & 31, hf = lane >> 5;
    float acc = 0.f;
#pragma unroll
    for (int j4 = 0; j4 < 49; j4++) {
      int j = hf * 196 + j4 * 4;
      float4 p4 = *(const float4*)&ps[wid][j];
      ushort4 v4 = *(const ushort4*)&Vt[d][j];
      acc += p4.x * b2f(v4.x) + p4.y * b2f(v4.y) + p4.z * b2f(v4.z) +
             p4.w * b2f(v4.w);
    }
    acc += __shfl_xor(acc, 32, 64);
    if (hf == 0)
      attno[((size_t)(widx * 392 + row)) * 256 + head * 32 + d] = f2b(acc);
    __syncthreads();
  }
}

extern "C" void kernel_launch(void* const* d_in, const int* in_sizes, int n_in,
                              void* d_out, int out_size, void* d_ws,
                              size_t ws_size, hipStream_t stream) {
  const float* x     = (const float*)d_in[0];
  const float* n1g   = (const float*)d_in[1];
  const float* n1b   = (const float*)d_in[2];
  const float* qkvw  = (const float*)d_in[3];
  const float* qkvb  = (const float*)d_in[4];
  const float* rpb   = (const float*)d_in[5];
  const float* projw = (const float*)d_in[6];
  const float* projb = (const float*)d_in[7];
  const float* n2g   = (const float*)d_in[8];
  const float* n2b   = (const float*)d_in[9];
  const float* fc1w  = (const float*)d_in[10];
  const float* fc1b  = (const float*)d_in[11];
  const float* fc2w  = (const float*)d_in[12];
  const float* fc2b  = (const float*)d_in[13];

  // Lifetime-aliased workspace (total 130,023,424 B):
  //   [0       , 25.69M)  xw (LN1 out)      -> attno (attn out) -> hid (low part)
  //   [25.69M  , 51.38M)  q                 -> h2 lives elsewhere; hid middle
  //   [51.38M  ,102.76M)  k,v               -> hid upper part
  //   hid = [0, 102.76M)  (written after everything in it is dead)
  //   [102.76M ,128.45M)  h2 (LN2 out)
  //   [128.45M ,130.02M)  bf16 weights
  // xres (fp32 residual) lives in d_out itself.
  const size_t NEED = 130023424;
  if (ws_size < NEED) return;  // diagnostic: absmax-fail (not crash) => ws too small

  char* ws = (char*)d_ws;
  u16* xw     = (u16*)(ws + 0LL);
  u16* qb     = (u16*)(ws + 25690112LL);
  // kb = qb + 12845056 elems, vb = qb + 2*12845056 (contiguous)
  u16* attno  = (u16*)(ws + 0LL);
  u16* hid    = (u16*)(ws + 0LL);
  u16* h2     = (u16*)(ws + 102760448LL);
  u16* wq     = (u16*)(ws + 128450560LL);
  u16* wp     = (u16*)(ws + 128843776LL);
  u16* w1     = (u16*)(ws + 128974848LL);
  u16* w2     = (u16*)(ws + 129499136LL);
  float* xres = (float*)d_out;

  castw<<<768, 256, 0, stream>>>(qkvw, wq, 196608);
  castw<<<256, 256, 0, stream>>>(projw, wp, 65536);
  castw<<<1024, 256, 0, stream>>>(fc1w, w1, 262144);
  castw<<<1024, 256, 0, stream>>>(fc2w, w2, 262144);

  ln_k<<<12544, 256, 0, stream>>>(x, n1g, n1b, xw, 1);
  gemm_k<0><<<392 * 6, 256, 0, stream>>>(xw, wq, 256, 6, qkvb, qb, nullptr,
                                         nullptr, 0.17677669529663687f);
  attn_k<<<1024, 256, 0, stream>>>(qb, qb + 12845056, qb + 2 * 12845056, rpb,
                                   attno);
  gemm_k<1><<<392 * 2, 256, 0, stream>>>(attno, wp, 256, 2, projb, nullptr,
                                         xres, x, 0.f);
  ln_k<<<12544, 256, 0, stream>>>(xres, n2g, n2b, h2, 0);
  gemm_k<2><<<392 * 8, 256, 0, stream>>>(h2, w1, 256, 8, fc1b, hid, nullptr,
                                         nullptr, 0.f);
  gemm_k<3><<<392 * 2, 256, 0, stream>>>(hid, w2, 1024, 2, fc2b, nullptr,
                                         (float*)d_out, xres, 0.f);
}

// Round 4
// 417.423 us; speedup vs baseline: 2.9399x; 2.9399x over previous
//
#include <hip/hip_runtime.h>
#include <hip/hip_bf16.h>
#include <cmath>

typedef unsigned short u16;
typedef unsigned int u32;

using bf16x8 = __attribute__((ext_vector_type(8))) short;
using f32x4  = __attribute__((ext_vector_type(4))) float;

__device__ __forceinline__ float b2f(u16 u) {
  union { u32 i; float f; } x; x.i = ((u32)u) << 16; return x.f;
}
__device__ __forceinline__ u16 f2b(float f) {
  union { float f; u32 i; } x; x.f = f;
  u32 r = x.i + 0x7fffu + ((x.i >> 16) & 1u);
  return (u16)(r >> 16);
}
__device__ __forceinline__ u32 cvtpk(float lo, float hi) {
  u32 r;
  asm("v_cvt_pk_bf16_f32 %0, %1, %2" : "=v"(r) : "v"(lo), "v"(hi));
  return r;
}

// ---------------- weight cast fp32 -> bf16 ----------------
__global__ __launch_bounds__(256) void castw(const float* __restrict__ a,
                                             u16* __restrict__ o, int n) {
  int i = blockIdx.x * 256 + threadIdx.x;
  if (i < n) o[i] = f2b(a[i]);
}

// ---------------- relative-position bias table: [8][392][400] bf16 --------
__global__ __launch_bounds__(256) void bias_k(const float* __restrict__ rpb,
                                              u16* __restrict__ biasT) {
  int b = blockIdx.x;  // h*392 + q
  int h = b / 392, q = b - h * 392;
  int ti = q / 49, rem = q - ti * 49, hi = rem / 7, wi = rem - hi * 7;
  int cq = ti * 169 + hi * 13 + wi;
  for (int k = threadIdx.x; k < 400; k += 256) {
    u16 v = 0;
    if (k < 392) {
      int tk = k / 49, rk = k - tk * 49, hk = rk / 7, wk = rk - hk * 7;
      int ck = tk * 169 + hk * 13 + wk;
      v = f2b(rpb[(cq - ck + 1267) * 8 + h]);
    }
    biasT[(size_t)b * 400 + k] = v;
  }
}

// ---------------- LayerNorm (+ optional roll+window-partition gather) ------
__global__ __launch_bounds__(256) void ln_k(const float* __restrict__ src,
                                            const float* __restrict__ g,
                                            const float* __restrict__ b,
                                            u16* __restrict__ dst, int shifted) {
  const int wid = threadIdx.x >> 6, lane = threadIdx.x & 63;
  const int row = blockIdx.x * 4 + wid;
  int srow;
  if (shifted) {
    int widx = row / 392, n = row - widx * 392;
    int wt = widx >> 6, wh = (widx >> 3) & 7, ww = widx & 7;
    int ti = n / 49, rem = n - ti * 49, hi = rem / 7, wi = rem - hi * 7;
    int t = (wt * 8 + ti + 4) & 15;
    int h = wh * 7 + hi + 3; if (h >= 56) h -= 56;
    int w = ww * 7 + wi + 3; if (w >= 56) w -= 56;
    srow = (t * 56 + h) * 56 + w;
  } else {
    srow = row;
  }
  float4 v = *(const float4*)(src + (size_t)srow * 256 + lane * 4);
  float s = v.x + v.y + v.z + v.w;
  float sq = v.x * v.x + v.y * v.y + v.z * v.z + v.w * v.w;
  for (int o = 1; o < 64; o <<= 1) {
    s += __shfl_xor(s, o, 64);
    sq += __shfl_xor(sq, o, 64);
  }
  float mu = s * (1.0f / 256.0f);
  float rstd = rsqrtf(sq * (1.0f / 256.0f) - mu * mu + 1e-5f);
  float4 gg = *(const float4*)(g + lane * 4);
  float4 bb = *(const float4*)(b + lane * 4);
  ushort4 ov;
  ov.x = f2b((v.x - mu) * rstd * gg.x + bb.x);
  ov.y = f2b((v.y - mu) * rstd * gg.y + bb.y);
  ov.z = f2b((v.z - mu) * rstd * gg.z + bb.z);
  ov.w = f2b((v.w - mu) * rstd * gg.w + bb.w);
  *(ushort4*)(dst + (size_t)row * 256 + lane * 4) = ov;
}

// ---------------- MFMA GEMM: C = A(MxK) @ B(NxK)^T, templated epilogue -----
template <int EPI>
__global__ __launch_bounds__(256) void gemm_k(const u16* __restrict__ A,
                                              const u16* __restrict__ Bw, int K,
                                              int tilesN,
                                              const float* __restrict__ bias,
                                              u16* __restrict__ outb,
                                              float* __restrict__ outf,
                                              const float* __restrict__ res,
                                              float qscale) {
  __shared__ __align__(16) u16 As[128][40];
  __shared__ __align__(16) u16 Bs[128][40];
  const int tid = threadIdx.x;
  const int tm = blockIdx.x / tilesN, tn = blockIdx.x % tilesN;
  const int wid = tid >> 6, lane = tid & 63;
  const int wm = wid >> 1, wn = wid & 1;
  const int lm = lane & 15, lk = lane >> 4;
  f32x4 acc[4][4] = {};
  const u16* Ap = A + (size_t)tm * 128 * K;
  const u16* Bp = Bw + (size_t)tn * 128 * K;
  const int r0 = tid >> 2, cg0 = (tid & 3) * 8;
  for (int k0 = 0; k0 < K; k0 += 32) {
    __syncthreads();
    *(bf16x8*)&As[r0][cg0]      = *(const bf16x8*)(Ap + (size_t)r0 * K + k0 + cg0);
    *(bf16x8*)&As[r0 + 64][cg0] = *(const bf16x8*)(Ap + (size_t)(r0 + 64) * K + k0 + cg0);
    *(bf16x8*)&Bs[r0][cg0]      = *(const bf16x8*)(Bp + (size_t)r0 * K + k0 + cg0);
    *(bf16x8*)&Bs[r0 + 64][cg0] = *(const bf16x8*)(Bp + (size_t)(r0 + 64) * K + k0 + cg0);
    __syncthreads();
    bf16x8 af[4], bfr[4];
#pragma unroll
    for (int f = 0; f < 4; f++) {
      af[f]  = *(const bf16x8*)&As[wm * 64 + f * 16 + lm][lk * 8];
      bfr[f] = *(const bf16x8*)&Bs[wn * 64 + f * 16 + lm][lk * 8];
    }
#pragma unroll
    for (int fm = 0; fm < 4; fm++)
#pragma unroll
      for (int fn = 0; fn < 4; fn++)
        acc[fm][fn] = __builtin_amdgcn_mfma_f32_16x16x32_bf16(
            af[fm], bfr[fn], acc[fm][fn], 0, 0, 0);
  }
  const int rbase = tm * 128 + wm * 64, cbase = tn * 128 + wn * 64;
#pragma unroll
  for (int fm = 0; fm < 4; fm++) {
#pragma unroll
    for (int fn = 0; fn < 4; fn++) {
      const int col = cbase + fn * 16 + lm;
#pragma unroll
      for (int r = 0; r < 4; r++) {
        const int row = rbase + fm * 16 + lk * 4 + r;
        float v = acc[fm][fn][r] + bias[col];
        if (EPI == 0) {
          int s = col >> 8, rem = col & 255, head = rem >> 5, d = rem & 31;
          if (s == 0) v *= qscale;
          int widx = row / 392, n = row - widx * 392;
          size_t o = (size_t)s * 12845056u +
                     (((size_t)(widx * 8 + head)) * 392 + n) * 32 + d;
          outb[o] = f2b(v);
        } else if (EPI == 1) {
          int widx = row / 392, n = row - widx * 392;
          int wt = widx >> 6, wh = (widx >> 3) & 7, ww = widx & 7;
          int ti = n / 49, rem2 = n - ti * 49, hi = rem2 / 7, wi = rem2 - hi * 7;
          int t = (wt * 8 + ti + 4) & 15;
          int h = wh * 7 + hi + 3; if (h >= 56) h -= 56;
          int w = ww * 7 + wi + 3; if (w >= 56) w -= 56;
          size_t dr = ((size_t)(t * 56 + h)) * 56 + w;
          outf[dr * 256 + col] = res[dr * 256 + col] + v;
        } else if (EPI == 2) {
          float gv = 0.5f * v * (1.0f + erff(v * 0.70710678f));
          outb[(size_t)row * 1024 + col] = f2b(gv);
        } else {
          outf[(size_t)row * 256 + col] = res[(size_t)row * 256 + col] + v;
        }
      }
    }
  }
}

// ---------------- MFMA windowed attention, block per (window, head) -------
// S^T = mfma(K,Q): lane (g,lm) holds S[key=16t+4g+r][q=qt*16+lm] -> softmax
// is lane-local + shfl_xor(16,32). P packed bf16 into per-wave XOR-swizzled
// LDS rows (q=lm), PV = mfma(P,Vt) in two 224-key passes.
__global__ __launch_bounds__(256) void attn_k(const u16* __restrict__ qg,
                                              const u16* __restrict__ kg,
                                              const u16* __restrict__ vg,
                                              const u16* __restrict__ biasT,
                                              u16* __restrict__ attno) {
  __shared__ __align__(16) char lds[62352];
  const int bid = blockIdx.x;  // widx*8 + head
  const int widx = bid >> 3, head = bid & 7;
  const int tid = threadIdx.x;
  const size_t base = (size_t)bid * 12544;

  // stage V transposed, chunk-blocked: [c][d][kk] rows of 80 B
  for (int idx = tid; idx < 392 * 8; idx += 256) {
    int j = idx >> 3, d4 = idx & 7;
    ushort4 v4 = *(const ushort4*)(vg + base + j * 32 + d4 * 4);
    int c = j >> 5, kk = j & 31;
    u16* p = (u16*)(lds + c * 2560 + d4 * 4 * 80 + kk * 2);
    p[0] = v4.x; p[40] = v4.y; p[80] = v4.z; p[120] = v4.w;
  }
  for (int idx = tid; idx < 768; idx += 256) {  // zero pad keys 392..415
    int d = idx / 24, kk = 8 + (idx - d * 24);
    *(u16*)(lds + 12 * 2560 + d * 80 + kk * 2) = 0;
  }
  {  // shifted-window region labels (grid-stride: fixes round-3 bug where
     // `if (tid<400)` left labels 256..399 uninitialized)
    int wt = widx >> 6, wh = (widx >> 3) & 7, ww = widx & 7;
    for (int i = tid; i < 400; i += 256) {
      unsigned char lab = 0;
      if (i < 392) {
        int ti = i / 49, rem = i - ti * 49, hi = rem / 7, wi = rem - hi * 7;
        int at = wt * 8 + ti, ah = wh * 7 + hi, aw = ww * 7 + wi;
        int rt = (at < 8) ? 0 : ((at < 12) ? 1 : 2);
        int rh = (ah < 49) ? 0 : ((ah < 53) ? 1 : 2);
        int rw = (aw < 49) ? 0 : ((aw < 53) ? 1 : 2);
        lab = (unsigned char)(rt * 9 + rh * 3 + rw);
      }
      lds[61952 + i] = (char)lab;
    }
  }
  __syncthreads();

  const int w = tid >> 6, lane = tid & 63;
  const int g = lane >> 4, lm = lane & 15;
  char* PqW = lds + 33280 + w * 7168 + lm * 448;
  const int swz = (lm & 3) << 4;
  const unsigned char* lab8 = (const unsigned char*)(lds + 61952);

  for (int qt = w; qt < 25; qt += 4) {
    const int q = qt * 16 + lm;
    const int qr = q < 391 ? q : 391;
    bf16x8 qf = *(const bf16x8*)(qg + base + (size_t)qr * 32 + g * 8);
    const int labq = lab8[qr];
    const u16* bp = biasT + ((size_t)(head * 392 + qr)) * 400 + 4 * g;
    const u16* kp = kg + base + g * 8;
    f32x4 st[25];
#pragma unroll
    for (int t = 0; t < 25; t++) {
      bf16x8 kf = *(const bf16x8*)(kp + (size_t)(t * 16 + lm) * 32);
      st[t] = __builtin_amdgcn_mfma_f32_16x16x32_bf16(
          kf, qf, (f32x4){0.f, 0.f, 0.f, 0.f}, 0, 0, 0);
    }
#pragma unroll
    for (int t = 0; t < 25; t++) {
      ushort4 bb = *(const ushort4*)(bp + t * 16);
      u32 l4 = *(const u32*)(lab8 + t * 16 + 4 * g);
      float s0 = st[t][0] + b2f(bb.x); if ((int)(l4 & 255u) != labq) s0 -= 100.f;
      float s1 = st[t][1] + b2f(bb.y); if ((int)((l4 >> 8) & 255u) != labq) s1 -= 100.f;
      float s2 = st[t][2] + b2f(bb.z); if ((int)((l4 >> 16) & 255u) != labq) s2 -= 100.f;
      float s3 = st[t][3] + b2f(bb.w); if ((int)(l4 >> 24) != labq) s3 -= 100.f;
      st[t][0] = s0; st[t][1] = s1; st[t][2] = s2; st[t][3] = s3;
    }
    if (g >= 2) {  // padded keys 392..399 live in tile 24, groups 2,3
      st[24][0] = st[24][1] = st[24][2] = st[24][3] = -1e30f;
    }
    float m = -3e38f;
#pragma unroll
    for (int t = 0; t < 25; t++)
      m = fmaxf(m, fmaxf(fmaxf(st[t][0], st[t][1]), fmaxf(st[t][2], st[t][3])));
    m = fmaxf(m, __shfl_xor(m, 16, 64));
    m = fmaxf(m, __shfl_xor(m, 32, 64));
    float sum = 0.f;
#pragma unroll
    for (int t = 0; t < 25; t++) {
      float e0 = __expf(st[t][0] - m), e1 = __expf(st[t][1] - m);
      float e2 = __expf(st[t][2] - m), e3 = __expf(st[t][3] - m);
      st[t][0] = e0; st[t][1] = e1; st[t][2] = e2; st[t][3] = e3;
      sum += (e0 + e1) + (e2 + e3);
    }
    sum += __shfl_xor(sum, 16, 64);
    sum += __shfl_xor(sum, 32, 64);
    const float inv = 1.f / sum;

    f32x4 oa0 = {0.f, 0.f, 0.f, 0.f}, oa1 = {0.f, 0.f, 0.f, 0.f};
    // ---- pass A: tiles 0..13 (keys 0..223), PV chunks 0..6
#pragma unroll
    for (int t = 0; t < 14; t++) {
      uint2 pp;
      pp.x = cvtpk(st[t][0] * inv, st[t][1] * inv);
      pp.y = cvtpk(st[t][2] * inv, st[t][3] * inv);
      *(uint2*)(PqW + ((32 * t + 8 * g) ^ swz)) = pp;
    }
    asm volatile("s_waitcnt lgkmcnt(0)" ::: "memory");
    __builtin_amdgcn_sched_barrier(0);
#pragma unroll
    for (int c = 0; c < 7; c++) {
      bf16x8 pf = *(const bf16x8*)(PqW + ((64 * c + 16 * g) ^ swz));
      bf16x8 v0 = *(const bf16x8*)(lds + c * 2560 + lm * 80 + g * 16);
      bf16x8 v1 = *(const bf16x8*)(lds + c * 2560 + (16 + lm) * 80 + g * 16);
      oa0 = __builtin_amdgcn_mfma_f32_16x16x32_bf16(pf, v0, oa0, 0, 0, 0);
      oa1 = __builtin_amdgcn_mfma_f32_16x16x32_bf16(pf, v1, oa1, 0, 0, 0);
    }
    __builtin_amdgcn_sched_barrier(0);
    // ---- pass B: tiles 14..25 (keys 224..415), PV chunks 7..12
#pragma unroll
    for (int t = 14; t < 26; t++) {
      uint2 pp;
      if (t < 25) {
        pp.x = cvtpk(st[t][0] * inv, st[t][1] * inv);
        pp.y = cvtpk(st[t][2] * inv, st[t][3] * inv);
      } else {
        pp.x = 0u; pp.y = 0u;  // keys 400..415
      }
      *(uint2*)(PqW + ((32 * t + 8 * g - 448) ^ swz)) = pp;
    }
    asm volatile("s_waitcnt lgkmcnt(0)" ::: "memory");
    __builtin_amdgcn_sched_barrier(0);
#pragma unroll
    for (int c = 7; c < 13; c++) {
      bf16x8 pf = *(const bf16x8*)(PqW + ((64 * c + 16 * g - 448) ^ swz));
      bf16x8 v0 = *(const bf16x8*)(lds + c * 2560 + lm * 80 + g * 16);
      bf16x8 v1 = *(const bf16x8*)(lds + c * 2560 + (16 + lm) * 80 + g * 16);
      oa0 = __builtin_amdgcn_mfma_f32_16x16x32_bf16(pf, v0, oa0, 0, 0, 0);
      oa1 = __builtin_amdgcn_mfma_f32_16x16x32_bf16(pf, v1, oa1, 0, 0, 0);
    }
#pragma unroll
    for (int r = 0; r < 4; r++) {
      int qq = qt * 16 + 4 * g + r;
      if (qq < 392) {
        u16* op = attno + ((size_t)(widx * 392 + qq)) * 256 + head * 32;
        op[lm] = f2b(oa0[r]);
        op[16 + lm] = f2b(oa1[r]);
      }
    }
  }
}

extern "C" void kernel_launch(void* const* d_in, const int* in_sizes, int n_in,
                              void* d_out, int out_size, void* d_ws,
                              size_t ws_size, hipStream_t stream) {
  const float* x     = (const float*)d_in[0];
  const float* n1g   = (const float*)d_in[1];
  const float* n1b   = (const float*)d_in[2];
  const float* qkvw  = (const float*)d_in[3];
  const float* qkvb  = (const float*)d_in[4];
  const float* rpb   = (const float*)d_in[5];
  const float* projw = (const float*)d_in[6];
  const float* projb = (const float*)d_in[7];
  const float* n2g   = (const float*)d_in[8];
  const float* n2b   = (const float*)d_in[9];
  const float* fc1w  = (const float*)d_in[10];
  const float* fc1b  = (const float*)d_in[11];
  const float* fc2w  = (const float*)d_in[12];
  const float* fc2b  = (const float*)d_in[13];

  // Lifetime-aliased workspace (total 130,023,424 B):
  //   [0, 25.69M)        xw -> attno -> hid(low)
  //   [25.69M, 102.76M)  q,k,v -> hid(high)
  //   [102.76M, 128.45M) biasT (attn phase) -> h2 (MLP phase)
  //   [128.45M, 130.02M) bf16 weights
  // xres (fp32 residual) lives in d_out.
  const size_t NEED = 130023424;
  if (ws_size < NEED) return;

  char* ws = (char*)d_ws;
  u16* xw     = (u16*)(ws + 0LL);
  u16* qb     = (u16*)(ws + 25690112LL);
  u16* attno  = (u16*)(ws + 0LL);
  u16* hid    = (u16*)(ws + 0LL);
  u16* biasT  = (u16*)(ws + 102760448LL);
  u16* h2     = (u16*)(ws + 102760448LL);
  u16* wq     = (u16*)(ws + 128450560LL);
  u16* wp     = (u16*)(ws + 128843776LL);
  u16* w1     = (u16*)(ws + 128974848LL);
  u16* w2     = (u16*)(ws + 129499136LL);
  float* xres = (float*)d_out;

  castw<<<768, 256, 0, stream>>>(qkvw, wq, 196608);
  castw<<<256, 256, 0, stream>>>(projw, wp, 65536);
  castw<<<1024, 256, 0, stream>>>(fc1w, w1, 262144);
  castw<<<1024, 256, 0, stream>>>(fc2w, w2, 262144);
  bias_k<<<3136, 256, 0, stream>>>(rpb, biasT);

  ln_k<<<12544, 256, 0, stream>>>(x, n1g, n1b, xw, 1);
  gemm_k<0><<<392 * 6, 256, 0, stream>>>(xw, wq, 256, 6, qkvb, qb, nullptr,
                                         nullptr, 0.17677669529663687f);
  attn_k<<<1024, 256, 0, stream>>>(qb, qb + 12845056, qb + 2 * 12845056, biasT,
                                   attno);
  gemm_k<1><<<392 * 2, 256, 0, stream>>>(attno, wp, 256, 2, projb, nullptr,
                                         xres, x, 0.f);
  ln_k<<<12544, 256, 0, stream>>>(xres, n2g, n2b, h2, 0);
  gemm_k<2><<<392 * 8, 256, 0, stream>>>(h2, w1, 256, 8, fc1b, hid, nullptr,
                                         nullptr, 0.f);
  gemm_k<3><<<392 * 2, 256, 0, stream>>>(hid, w2, 1024, 2, fc2b, nullptr,
                                         (float*)d_out, xres, 0.f);
}

// Round 5
// 400.891 us; speedup vs baseline: 3.0611x; 1.0412x over previous
//
#include <hip/hip_runtime.h>
#include <hip/hip_bf16.h>
#include <cmath>

typedef unsigned short u16;
typedef unsigned int u32;

using bf16x8 = __attribute__((ext_vector_type(8))) short;
using f32x4  = __attribute__((ext_vector_type(4))) float;

__device__ __forceinline__ float b2f(u16 u) {
  union { u32 i; float f; } x; x.i = ((u32)u) << 16; return x.f;
}
__device__ __forceinline__ u16 f2b(float f) {
  union { float f; u32 i; } x; x.f = f;
  u32 r = x.i + 0x7fffu + ((x.i >> 16) & 1u);
  return (u16)(r >> 16);
}
__device__ __forceinline__ u32 cvtpk(float lo, float hi) {
  u32 r;
  asm("v_cvt_pk_bf16_f32 %0, %1, %2" : "=v"(r) : "v"(lo), "v"(hi));
  return r;
}
__device__ __forceinline__ void gload_lds16(const u16* g, u16* l) {
  __builtin_amdgcn_global_load_lds(
      (const __attribute__((address_space(1))) unsigned int*)g,
      (__attribute__((address_space(3))) unsigned int*)l, 16, 0, 0);
}

// ---------------- weight cast fp32 -> bf16 ----------------
__global__ __launch_bounds__(256) void castw(const float* __restrict__ a,
                                             u16* __restrict__ o, int n) {
  int i = blockIdx.x * 256 + threadIdx.x;
  if (i < n) o[i] = f2b(a[i]);
}

// ---------------- relative-position bias table: [8][392][400] bf16 --------
__global__ __launch_bounds__(256) void bias_k(const float* __restrict__ rpb,
                                              u16* __restrict__ biasT) {
  int b = blockIdx.x;  // h*392 + q
  int h = b / 392, q = b - h * 392;
  int ti = q / 49, rem = q - ti * 49, hi = rem / 7, wi = rem - hi * 7;
  int cq = ti * 169 + hi * 13 + wi;
  for (int k = threadIdx.x; k < 400; k += 256) {
    u16 v = 0;
    if (k < 392) {
      int tk = k / 49, rk = k - tk * 49, hk = rk / 7, wk = rk - hk * 7;
      int ck = tk * 169 + hk * 13 + wk;
      v = f2b(rpb[(cq - ck + 1267) * 8 + h]);
    }
    biasT[(size_t)b * 400 + k] = v;
  }
}

// ---------------- LayerNorm (+ optional roll+window-partition gather) ------
__global__ __launch_bounds__(256) void ln_k(const float* __restrict__ src,
                                            const float* __restrict__ g,
                                            const float* __restrict__ b,
                                            u16* __restrict__ dst, int shifted) {
  const int wid = threadIdx.x >> 6, lane = threadIdx.x & 63;
  const int row = blockIdx.x * 4 + wid;
  int srow;
  if (shifted) {
    int widx = row / 392, n = row - widx * 392;
    int wt = widx >> 6, wh = (widx >> 3) & 7, ww = widx & 7;
    int ti = n / 49, rem = n - ti * 49, hi = rem / 7, wi = rem - hi * 7;
    int t = (wt * 8 + ti + 4) & 15;
    int h = wh * 7 + hi + 3; if (h >= 56) h -= 56;
    int w = ww * 7 + wi + 3; if (w >= 56) w -= 56;
    srow = (t * 56 + h) * 56 + w;
  } else {
    srow = row;
  }
  float4 v = *(const float4*)(src + (size_t)srow * 256 + lane * 4);
  float s = v.x + v.y + v.z + v.w;
  float sq = v.x * v.x + v.y * v.y + v.z * v.z + v.w * v.w;
  for (int o = 1; o < 64; o <<= 1) {
    s += __shfl_xor(s, o, 64);
    sq += __shfl_xor(sq, o, 64);
  }
  float mu = s * (1.0f / 256.0f);
  float rstd = rsqrtf(sq * (1.0f / 256.0f) - mu * mu + 1e-5f);
  float4 gg = *(const float4*)(g + lane * 4);
  float4 bb = *(const float4*)(b + lane * 4);
  ushort4 ov;
  ov.x = f2b((v.x - mu) * rstd * gg.x + bb.x);
  ov.y = f2b((v.y - mu) * rstd * gg.y + bb.y);
  ov.z = f2b((v.z - mu) * rstd * gg.z + bb.z);
  ov.w = f2b((v.w - mu) * rstd * gg.w + bb.w);
  *(ushort4*)(dst + (size_t)row * 256 + lane * 4) = ov;
}

// ---------------- MFMA GEMM (m97 structure): C = A(MxK) @ B(NxK)^T --------
// 128x128 tile, BK=64, global_load_lds dwordx4 staging into linear LDS with
// XOR-swizzle applied via pre-swizzled global source (c8 ^= row&7), reads
// apply the same swizzle -> conflict-free-ish ds_read_b128.
template <int EPI>
__global__ __launch_bounds__(256) void gemm_k(const u16* __restrict__ A,
                                              const u16* __restrict__ Bw, int K,
                                              int tilesN,
                                              const float* __restrict__ bias,
                                              u16* __restrict__ outb,
                                              float* __restrict__ outf,
                                              const float* __restrict__ res,
                                              float qscale) {
  __shared__ __align__(16) u16 As[128 * 64];
  __shared__ __align__(16) u16 Bs[128 * 64];
  const int tid = threadIdx.x;
  const int tm = blockIdx.x / tilesN, tn = blockIdx.x % tilesN;
  const int wid = tid >> 6, lane = tid & 63;
  const int wm = wid >> 1, wn = wid & 1;
  const int lm = lane & 15, lk = lane >> 4;
  f32x4 acc[4][4] = {};
  const u16* Ap = A + (size_t)tm * 128 * K;
  const u16* Bp = Bw + (size_t)tn * 128 * K;

  // staging geometry: wave wid covers rows [wid*32, wid*32+32), issue j adds 8
  const int sr_off = (lane >> 3);       // 0..7
  const int sc_lo = lane & 7;
  u16* alp = As + wid * 2048;           // bytes: wid*4096
  u16* blp = Bs + wid * 2048;

  for (int k0 = 0; k0 < K; k0 += 64) {
    __syncthreads();
#pragma unroll
    for (int j = 0; j < 4; j++) {
      int r = wid * 32 + j * 8 + sr_off;
      int c8 = sc_lo ^ (r & 7);
      const u16* ga = Ap + (size_t)r * K + k0 + c8 * 8;
      const u16* gb = Bp + (size_t)r * K + k0 + c8 * 8;
      gload_lds16(ga, alp + j * 512);
      gload_lds16(gb, blp + j * 512);
    }
    __syncthreads();  // drains vmcnt(0) before barrier (HIP semantics)
#pragma unroll
    for (int ks = 0; ks < 2; ks++) {
      bf16x8 af[4], bfr[4];
#pragma unroll
      for (int f = 0; f < 4; f++) {
        int ra = wm * 64 + f * 16 + lm;
        int rb = wn * 64 + f * 16 + lm;
        af[f] = *(const bf16x8*)((const char*)As + ra * 128 +
                                 (((ks * 4 + lk) ^ (ra & 7)) << 4));
        bfr[f] = *(const bf16x8*)((const char*)Bs + rb * 128 +
                                  (((ks * 4 + lk) ^ (rb & 7)) << 4));
      }
#pragma unroll
      for (int fm = 0; fm < 4; fm++)
#pragma unroll
        for (int fn = 0; fn < 4; fn++)
          acc[fm][fn] = __builtin_amdgcn_mfma_f32_16x16x32_bf16(
              af[fm], bfr[fn], acc[fm][fn], 0, 0, 0);
    }
  }
  const int rbase = tm * 128 + wm * 64, cbase = tn * 128 + wn * 64;
#pragma unroll
  for (int fm = 0; fm < 4; fm++) {
#pragma unroll
    for (int fn = 0; fn < 4; fn++) {
      const int col = cbase + fn * 16 + lm;
#pragma unroll
      for (int r = 0; r < 4; r++) {
        const int row = rbase + fm * 16 + lk * 4 + r;
        float v = acc[fm][fn][r] + bias[col];
        if (EPI == 0) {
          int s = col >> 8, rem = col & 255, head = rem >> 5, d = rem & 31;
          if (s == 0) v *= qscale;
          int widx = row / 392, n = row - widx * 392;
          size_t o = (size_t)s * 12845056u +
                     (((size_t)(widx * 8 + head)) * 392 + n) * 32 + d;
          outb[o] = f2b(v);
        } else if (EPI == 1) {
          int widx = row / 392, n = row - widx * 392;
          int wt = widx >> 6, wh = (widx >> 3) & 7, ww = widx & 7;
          int ti = n / 49, rem2 = n - ti * 49, hi = rem2 / 7, wi = rem2 - hi * 7;
          int t = (wt * 8 + ti + 4) & 15;
          int h = wh * 7 + hi + 3; if (h >= 56) h -= 56;
          int w = ww * 7 + wi + 3; if (w >= 56) w -= 56;
          size_t dr = ((size_t)(t * 56 + h)) * 56 + w;
          outf[dr * 256 + col] = res[dr * 256 + col] + v;
        } else if (EPI == 2) {
          float gv = 0.5f * v * (1.0f + erff(v * 0.70710678f));
          outb[(size_t)row * 1024 + col] = f2b(gv);
        } else {
          outf[(size_t)row * 256 + col] = res[(size_t)row * 256 + col] + v;
        }
      }
    }
  }
}

// ---------------- MFMA windowed attention, block per (window, head) -------
__global__ __launch_bounds__(256) void attn_k(const u16* __restrict__ qg,
                                              const u16* __restrict__ kg,
                                              const u16* __restrict__ vg,
                                              const u16* __restrict__ biasT,
                                              u16* __restrict__ attno) {
  __shared__ __align__(16) char lds[62352];
  const int bid = blockIdx.x;  // widx*8 + head
  const int widx = bid >> 3, head = bid & 7;
  const int tid = threadIdx.x;
  const size_t base = (size_t)bid * 12544;

  // stage V transposed, chunk-blocked: [c][d][kk] rows of 80 B
  for (int idx = tid; idx < 392 * 8; idx += 256) {
    int j = idx >> 3, d4 = idx & 7;
    ushort4 v4 = *(const ushort4*)(vg + base + j * 32 + d4 * 4);
    int c = j >> 5, kk = j & 31;
    u16* p = (u16*)(lds + c * 2560 + d4 * 4 * 80 + kk * 2);
    p[0] = v4.x; p[40] = v4.y; p[80] = v4.z; p[120] = v4.w;
  }
  for (int idx = tid; idx < 768; idx += 256) {  // zero pad keys 392..415
    int d = idx / 24, kk = 8 + (idx - d * 24);
    *(u16*)(lds + 12 * 2560 + d * 80 + kk * 2) = 0;
  }
  {  // shifted-window region labels
    int wt = widx >> 6, wh = (widx >> 3) & 7, ww = widx & 7;
    for (int i = tid; i < 400; i += 256) {
      unsigned char lab = 0;
      if (i < 392) {
        int ti = i / 49, rem = i - ti * 49, hi = rem / 7, wi = rem - hi * 7;
        int at = wt * 8 + ti, ah = wh * 7 + hi, aw = ww * 7 + wi;
        int rt = (at < 8) ? 0 : ((at < 12) ? 1 : 2);
        int rh = (ah < 49) ? 0 : ((ah < 53) ? 1 : 2);
        int rw = (aw < 49) ? 0 : ((aw < 53) ? 1 : 2);
        lab = (unsigned char)(rt * 9 + rh * 3 + rw);
      }
      lds[61952 + i] = (char)lab;
    }
  }
  __syncthreads();

  const int w = tid >> 6, lane = tid & 63;
  const int g = lane >> 4, lm = lane & 15;
  char* PqW = lds + 33280 + w * 7168 + lm * 448;
  // swizzle key: row stride 448B => base bank 16*(lm&1); XOR must inject lm
  // bits 1-2 (not 0-1!) so lanes lm,lm+4 don't collide. Residual 2-way
  // (lm vs lm+8) is free (m136).
  const int swz = ((lm >> 1) & 3) << 4;
  const unsigned char* lab8 = (const unsigned char*)(lds + 61952);

  for (int qt = w; qt < 25; qt += 4) {
    const int q = qt * 16 + lm;
    const int qr = q < 391 ? q : 391;
    bf16x8 qf = *(const bf16x8*)(qg + base + (size_t)qr * 32 + g * 8);
    const int labq = lab8[qr];
    const u16* bp = biasT + ((size_t)(head * 392 + qr)) * 400 + 4 * g;
    const u16* kp = kg + base + g * 8;
    f32x4 st[25];
#pragma unroll
    for (int t = 0; t < 25; t++) {
      bf16x8 kf = *(const bf16x8*)(kp + (size_t)(t * 16 + lm) * 32);
      st[t] = __builtin_amdgcn_mfma_f32_16x16x32_bf16(
          kf, qf, (f32x4){0.f, 0.f, 0.f, 0.f}, 0, 0, 0);
    }
#pragma unroll
    for (int t = 0; t < 25; t++) {
      ushort4 bb = *(const ushort4*)(bp + t * 16);
      u32 l4 = *(const u32*)(lab8 + t * 16 + 4 * g);
      float s0 = st[t][0] + b2f(bb.x); if ((int)(l4 & 255u) != labq) s0 -= 100.f;
      float s1 = st[t][1] + b2f(bb.y); if ((int)((l4 >> 8) & 255u) != labq) s1 -= 100.f;
      float s2 = st[t][2] + b2f(bb.z); if ((int)((l4 >> 16) & 255u) != labq) s2 -= 100.f;
      float s3 = st[t][3] + b2f(bb.w); if ((int)(l4 >> 24) != labq) s3 -= 100.f;
      st[t][0] = s0; st[t][1] = s1; st[t][2] = s2; st[t][3] = s3;
    }
    if (g >= 2) {  // padded keys 392..399 live in tile 24, groups 2,3
      st[24][0] = st[24][1] = st[24][2] = st[24][3] = -1e30f;
    }
    float m = -3e38f;
#pragma unroll
    for (int t = 0; t < 25; t++)
      m = fmaxf(m, fmaxf(fmaxf(st[t][0], st[t][1]), fmaxf(st[t][2], st[t][3])));
    m = fmaxf(m, __shfl_xor(m, 16, 64));
    m = fmaxf(m, __shfl_xor(m, 32, 64));
    float sum = 0.f;
#pragma unroll
    for (int t = 0; t < 25; t++) {
      float e0 = __expf(st[t][0] - m), e1 = __expf(st[t][1] - m);
      float e2 = __expf(st[t][2] - m), e3 = __expf(st[t][3] - m);
      st[t][0] = e0; st[t][1] = e1; st[t][2] = e2; st[t][3] = e3;
      sum += (e0 + e1) + (e2 + e3);
    }
    sum += __shfl_xor(sum, 16, 64);
    sum += __shfl_xor(sum, 32, 64);
    const float inv = 1.f / sum;

    f32x4 oa0 = {0.f, 0.f, 0.f, 0.f}, oa1 = {0.f, 0.f, 0.f, 0.f};
    // ---- pass A: tiles 0..13 (keys 0..223), PV chunks 0..6
#pragma unroll
    for (int t = 0; t < 14; t++) {
      uint2 pp;
      pp.x = cvtpk(st[t][0] * inv, st[t][1] * inv);
      pp.y = cvtpk(st[t][2] * inv, st[t][3] * inv);
      *(uint2*)(PqW + ((32 * t + 8 * g) ^ swz)) = pp;
    }
    asm volatile("s_waitcnt lgkmcnt(0)" ::: "memory");
    __builtin_amdgcn_sched_barrier(0);
#pragma unroll
    for (int c = 0; c < 7; c++) {
      bf16x8 pf = *(const bf16x8*)(PqW + ((64 * c + 16 * g) ^ swz));
      bf16x8 v0 = *(const bf16x8*)(lds + c * 2560 + lm * 80 + g * 16);
      bf16x8 v1 = *(const bf16x8*)(lds + c * 2560 + (16 + lm) * 80 + g * 16);
      oa0 = __builtin_amdgcn_mfma_f32_16x16x32_bf16(pf, v0, oa0, 0, 0, 0);
      oa1 = __builtin_amdgcn_mfma_f32_16x16x32_bf16(pf, v1, oa1, 0, 0, 0);
    }
    __builtin_amdgcn_sched_barrier(0);
    // ---- pass B: tiles 14..25 (keys 224..415), PV chunks 7..12
#pragma unroll
    for (int t = 14; t < 26; t++) {
      uint2 pp;
      if (t < 25) {
        pp.x = cvtpk(st[t][0] * inv, st[t][1] * inv);
        pp.y = cvtpk(st[t][2] * inv, st[t][3] * inv);
      } else {
        pp.x = 0u; pp.y = 0u;  // keys 400..415
      }
      *(uint2*)(PqW + ((32 * t + 8 * g - 448) ^ swz)) = pp;
    }
    asm volatile("s_waitcnt lgkmcnt(0)" ::: "memory");
    __builtin_amdgcn_sched_barrier(0);
#pragma unroll
    for (int c = 7; c < 13; c++) {
      bf16x8 pf = *(const bf16x8*)(PqW + ((64 * c + 16 * g - 448) ^ swz));
      bf16x8 v0 = *(const bf16x8*)(lds + c * 2560 + lm * 80 + g * 16);
      bf16x8 v1 = *(const bf16x8*)(lds + c * 2560 + (16 + lm) * 80 + g * 16);
      oa0 = __builtin_amdgcn_mfma_f32_16x16x32_bf16(pf, v0, oa0, 0, 0, 0);
      oa1 = __builtin_amdgcn_mfma_f32_16x16x32_bf16(pf, v1, oa1, 0, 0, 0);
    }
#pragma unroll
    for (int r = 0; r < 4; r++) {
      int qq = qt * 16 + 4 * g + r;
      if (qq < 392) {
        u16* op = attno + ((size_t)(widx * 392 + qq)) * 256 + head * 32;
        op[lm] = f2b(oa0[r]);
        op[16 + lm] = f2b(oa1[r]);
      }
    }
  }
}

extern "C" void kernel_launch(void* const* d_in, const int* in_sizes, int n_in,
                              void* d_out, int out_size, void* d_ws,
                              size_t ws_size, hipStream_t stream) {
  const float* x     = (const float*)d_in[0];
  const float* n1g   = (const float*)d_in[1];
  const float* n1b   = (const float*)d_in[2];
  const float* qkvw  = (const float*)d_in[3];
  const float* qkvb  = (const float*)d_in[4];
  const float* rpb   = (const float*)d_in[5];
  const float* projw = (const float*)d_in[6];
  const float* projb = (const float*)d_in[7];
  const float* n2g   = (const float*)d_in[8];
  const float* n2b   = (const float*)d_in[9];
  const float* fc1w  = (const float*)d_in[10];
  const float* fc1b  = (const float*)d_in[11];
  const float* fc2w  = (const float*)d_in[12];
  const float* fc2b  = (const float*)d_in[13];

  // Lifetime-aliased workspace (total 130,023,424 B):
  //   [0, 25.69M)        xw -> attno -> hid(low)
  //   [25.69M, 102.76M)  q,k,v -> hid(high)
  //   [102.76M, 128.45M) biasT (attn phase) -> h2 (MLP phase)
  //   [128.45M, 130.02M) bf16 weights
  // xres (fp32 residual) lives in d_out.
  const size_t NEED = 130023424;
  if (ws_size < NEED) return;

  char* ws = (char*)d_ws;
  u16* xw     = (u16*)(ws + 0LL);
  u16* qb     = (u16*)(ws + 25690112LL);
  u16* attno  = (u16*)(ws + 0LL);
  u16* hid    = (u16*)(ws + 0LL);
  u16* biasT  = (u16*)(ws + 102760448LL);
  u16* h2     = (u16*)(ws + 102760448LL);
  u16* wq     = (u16*)(ws + 128450560LL);
  u16* wp     = (u16*)(ws + 128843776LL);
  u16* w1     = (u16*)(ws + 128974848LL);
  u16* w2     = (u16*)(ws + 129499136LL);
  float* xres = (float*)d_out;

  castw<<<768, 256, 0, stream>>>(qkvw, wq, 196608);
  castw<<<256, 256, 0, stream>>>(projw, wp, 65536);
  castw<<<1024, 256, 0, stream>>>(fc1w, w1, 262144);
  castw<<<1024, 256, 0, stream>>>(fc2w, w2, 262144);
  bias_k<<<3136, 256, 0, stream>>>(rpb, biasT);

  ln_k<<<12544, 256, 0, stream>>>(x, n1g, n1b, xw, 1);
  gemm_k<0><<<392 * 6, 256, 0, stream>>>(xw, wq, 256, 6, qkvb, qb, nullptr,
                                         nullptr, 0.17677669529663687f);
  attn_k<<<1024, 256, 0, stream>>>(qb, qb + 12845056, qb + 2 * 12845056, biasT,
                                   attno);
  gemm_k<1><<<392 * 2, 256, 0, stream>>>(attno, wp, 256, 2, projb, nullptr,
                                         xres, x, 0.f);
  ln_k<<<12544, 256, 0, stream>>>(xres, n2g, n2b, h2, 0);
  gemm_k<2><<<392 * 8, 256, 0, stream>>>(h2, w1, 256, 8, fc1b, hid, nullptr,
                                         nullptr, 0.f);
  gemm_k<3><<<392 * 2, 256, 0, stream>>>(hid, w2, 1024, 2, fc2b, nullptr,
                                         (float*)d_out, xres, 0.f);
}

// Round 6
// 389.918 us; speedup vs baseline: 3.1473x; 1.0281x over previous
//
#include <hip/hip_runtime.h>
#include <hip/hip_bf16.h>
#include <cmath>

typedef unsigned short u16;
typedef unsigned int u32;

using bf16x8 = __attribute__((ext_vector_type(8))) short;
using f32x4  = __attribute__((ext_vector_type(4))) float;

__device__ __forceinline__ float b2f(u16 u) {
  union { u32 i; float f; } x; x.i = ((u32)u) << 16; return x.f;
}
__device__ __forceinline__ u16 f2b(float f) {
  union { float f; u32 i; } x; x.f = f;
  u32 r = x.i + 0x7fffu + ((x.i >> 16) & 1u);
  return (u16)(r >> 16);
}
__device__ __forceinline__ u32 cvtpk(float lo, float hi) {
  u32 r;
  asm("v_cvt_pk_bf16_f32 %0, %1, %2" : "=v"(r) : "v"(lo), "v"(hi));
  return r;
}
__device__ __forceinline__ float vexp2(float x) {
  float r;
  asm("v_exp_f32 %0, %1" : "=v"(r) : "v"(x));
  return r;
}
__device__ __forceinline__ void gload_lds16(const u16* g, u16* l) {
  __builtin_amdgcn_global_load_lds(
      (const __attribute__((address_space(1))) unsigned int*)g,
      (__attribute__((address_space(3))) unsigned int*)l, 16, 0, 0);
}

// ---------------- weight cast fp32 -> bf16 ----------------
__global__ __launch_bounds__(256) void castw(const float* __restrict__ a,
                                             u16* __restrict__ o, int n) {
  int i = blockIdx.x * 256 + threadIdx.x;
  if (i < n) o[i] = f2b(a[i]);
}

// ------- combined (bias+mask)*log2e table [8cls][8h][392][400] bf16 + rowmax
__global__ __launch_bounds__(256) void bias_k(const float* __restrict__ rpb,
                                              u16* __restrict__ biasM,
                                              float* __restrict__ rowmax) {
  const int b = blockIdx.x;  // ((cls*8+head)*392 + q)
  const int q = b % 392, sh = b / 392;
  const int head = sh & 7, cls = sh >> 3;
  const int tb = (cls >> 2) & 1, hb = (cls >> 1) & 1, wb = cls & 1;
  const int ti = q / 49, rem = q - ti * 49, hi = rem / 7, wi = rem - hi * 7;
  const int cq = ti * 169 + hi * 13 + wi;
  const int rtq = tb ? (ti < 4 ? 1 : 2) : 0;
  const int rhq = hb ? (hi < 4 ? 1 : 2) : 0;
  const int rwq = wb ? (wi < 4 ? 1 : 2) : 0;
  const int labq = rtq * 9 + rhq * 3 + rwq;
  const int tid = threadIdx.x;
  float mx = -3e38f;
  for (int k = tid; k < 400; k += 256) {
    float v;
    if (k < 392) {
      int tk = k / 49, rk = k - tk * 49, hk = rk / 7, wk = rk - hk * 7;
      int ck = tk * 169 + hk * 13 + wk;
      float bv = rpb[(cq - ck + 1267) * 8 + head];
      int rt = tb ? (tk < 4 ? 1 : 2) : 0;
      int rh = hb ? (hk < 4 ? 1 : 2) : 0;
      int rw = wb ? (wk < 4 ? 1 : 2) : 0;
      if (rt * 9 + rh * 3 + rw != labq) bv -= 100.f;
      v = bv * 1.4426950408889634f;
      mx = fmaxf(mx, v);
    } else {
      v = -2081.f;  // pad keys: exp2 -> exactly 0
    }
    biasM[(size_t)b * 400 + k] = f2b(v);
  }
  for (int o = 1; o < 64; o <<= 1) mx = fmaxf(mx, __shfl_xor(mx, o, 64));
  __shared__ float red[4];
  if ((tid & 63) == 0) red[tid >> 6] = mx;
  __syncthreads();
  if (tid == 0)
    rowmax[b] = fmaxf(fmaxf(red[0], red[1]), fmaxf(red[2], red[3]));
}

// ---------------- LayerNorm (+ optional roll+window-partition gather) ------
__global__ __launch_bounds__(256) void ln_k(const float* __restrict__ src,
                                            const float* __restrict__ g,
                                            const float* __restrict__ b,
                                            u16* __restrict__ dst, int shifted) {
  const int wid = threadIdx.x >> 6, lane = threadIdx.x & 63;
  const int row = blockIdx.x * 4 + wid;
  int srow;
  if (shifted) {
    int widx = row / 392, n = row - widx * 392;
    int wt = widx >> 6, wh = (widx >> 3) & 7, ww = widx & 7;
    int ti = n / 49, rem = n - ti * 49, hi = rem / 7, wi = rem - hi * 7;
    int t = (wt * 8 + ti + 4) & 15;
    int h = wh * 7 + hi + 3; if (h >= 56) h -= 56;
    int w = ww * 7 + wi + 3; if (w >= 56) w -= 56;
    srow = (t * 56 + h) * 56 + w;
  } else {
    srow = row;
  }
  float4 v = *(const float4*)(src + (size_t)srow * 256 + lane * 4);
  float s = v.x + v.y + v.z + v.w;
  float sq = v.x * v.x + v.y * v.y + v.z * v.z + v.w * v.w;
  for (int o = 1; o < 64; o <<= 1) {
    s += __shfl_xor(s, o, 64);
    sq += __shfl_xor(sq, o, 64);
  }
  float mu = s * (1.0f / 256.0f);
  float rstd = rsqrtf(sq * (1.0f / 256.0f) - mu * mu + 1e-5f);
  float4 gg = *(const float4*)(g + lane * 4);
  float4 bb = *(const float4*)(b + lane * 4);
  ushort4 ov;
  ov.x = f2b((v.x - mu) * rstd * gg.x + bb.x);
  ov.y = f2b((v.y - mu) * rstd * gg.y + bb.y);
  ov.z = f2b((v.z - mu) * rstd * gg.z + bb.z);
  ov.w = f2b((v.w - mu) * rstd * gg.w + bb.w);
  *(ushort4*)(dst + (size_t)row * 256 + lane * 4) = ov;
}

// ---------------- MFMA GEMM (m97 structure): C = A(MxK) @ B(NxK)^T --------
template <int EPI>
__global__ __launch_bounds__(256) void gemm_k(const u16* __restrict__ A,
                                              const u16* __restrict__ Bw, int K,
                                              int tilesN,
                                              const float* __restrict__ bias,
                                              u16* __restrict__ outb,
                                              float* __restrict__ outf,
                                              const float* __restrict__ res,
                                              float qscale) {
  __shared__ __align__(16) u16 As[128 * 64];
  __shared__ __align__(16) u16 Bs[128 * 64];
  const int tid = threadIdx.x;
  const int tm = blockIdx.x / tilesN, tn = blockIdx.x % tilesN;
  const int wid = tid >> 6, lane = tid & 63;
  const int wm = wid >> 1, wn = wid & 1;
  const int lm = lane & 15, lk = lane >> 4;
  f32x4 acc[4][4] = {};
  const u16* Ap = A + (size_t)tm * 128 * K;
  const u16* Bp = Bw + (size_t)tn * 128 * K;

  const int sr_off = (lane >> 3);
  const int sc_lo = lane & 7;
  u16* alp = As + wid * 2048;
  u16* blp = Bs + wid * 2048;

  for (int k0 = 0; k0 < K; k0 += 64) {
    __syncthreads();
#pragma unroll
    for (int j = 0; j < 4; j++) {
      int r = wid * 32 + j * 8 + sr_off;
      int c8 = sc_lo ^ (r & 7);
      gload_lds16(Ap + (size_t)r * K + k0 + c8 * 8, alp + j * 512);
      gload_lds16(Bp + (size_t)r * K + k0 + c8 * 8, blp + j * 512);
    }
    __syncthreads();
#pragma unroll
    for (int ks = 0; ks < 2; ks++) {
      bf16x8 af[4], bfr[4];
#pragma unroll
      for (int f = 0; f < 4; f++) {
        int ra = wm * 64 + f * 16 + lm;
        int rb = wn * 64 + f * 16 + lm;
        af[f] = *(const bf16x8*)((const char*)As + ra * 128 +
                                 (((ks * 4 + lk) ^ (ra & 7)) << 4));
        bfr[f] = *(const bf16x8*)((const char*)Bs + rb * 128 +
                                  (((ks * 4 + lk) ^ (rb & 7)) << 4));
      }
#pragma unroll
      for (int fm = 0; fm < 4; fm++)
#pragma unroll
        for (int fn = 0; fn < 4; fn++)
          acc[fm][fn] = __builtin_amdgcn_mfma_f32_16x16x32_bf16(
              af[fm], bfr[fn], acc[fm][fn], 0, 0, 0);
    }
  }
  const int rbase = tm * 128 + wm * 64, cbase = tn * 128 + wn * 64;
#pragma unroll
  for (int fm = 0; fm < 4; fm++) {
#pragma unroll
    for (int fn = 0; fn < 4; fn++) {
      const int col = cbase + fn * 16 + lm;
#pragma unroll
      for (int r = 0; r < 4; r++) {
        const int row = rbase + fm * 16 + lk * 4 + r;
        float v = acc[fm][fn][r] + bias[col];
        if (EPI == 0) {
          int s = col >> 8, rem = col & 255, head = rem >> 5, d = rem & 31;
          int widx = row / 392, n = row - widx * 392;
          size_t o;
          if (s == 2) {
            // v transposed: [bid*32+d][400], at elem offset 2*12845056
            o = 25690112u + (((size_t)(widx * 8 + head)) * 32 + d) * 400 + n;
          } else {
            if (s == 0) v *= qscale;
            o = (size_t)s * 12845056u +
                (((size_t)(widx * 8 + head)) * 392 + n) * 32 + d;
          }
          outb[o] = f2b(v);
        } else if (EPI == 1) {
          int widx = row / 392, n = row - widx * 392;
          int wt = widx >> 6, wh = (widx >> 3) & 7, ww = widx & 7;
          int ti = n / 49, rem2 = n - ti * 49, hi = rem2 / 7, wi = rem2 - hi * 7;
          int t = (wt * 8 + ti + 4) & 15;
          int h = wh * 7 + hi + 3; if (h >= 56) h -= 56;
          int w = ww * 7 + wi + 3; if (w >= 56) w -= 56;
          size_t dr = ((size_t)(t * 56 + h)) * 56 + w;
          outf[dr * 256 + col] = res[dr * 256 + col] + v;
        } else if (EPI == 2) {
          float gv = 0.5f * v * (1.0f + erff(v * 0.70710678f));
          outb[(size_t)row * 1024 + col] = f2b(gv);
        } else {
          outf[(size_t)row * 256 + col] = res[(size_t)row * 256 + col] + v;
        }
      }
    }
  }
}

// ---------------- MFMA windowed attention, block per (window, head) -------
// LDS: K [392 rows][64B, slot-swizzled] @0 (25088 B)
//      V^T [32 d][848 B rows, keys 0..415 + pad] @25088 (27136 B)
//      Pq per-wave [16 q][128 B, XOR-swz] @52224 (8192 B)  -> 60416 B total
// S^T = mfma(K,Q) from LDS; softmax in exp2 domain, m = max(S)+rowmax(bias)
// (safe upper bound), normalization deferred to output. PV in 7 passes of
// 64 keys through the small Pq buffer.
__global__ __launch_bounds__(256) void attn_k(const u16* __restrict__ qg,
                                              const u16* __restrict__ kg,
                                              const u16* __restrict__ vTg,
                                              const u16* __restrict__ biasM,
                                              const float* __restrict__ rowmax,
                                              u16* __restrict__ attno) {
  __shared__ __align__(16) char lds[60416];
  const int bid = blockIdx.x;  // widx*8 + head
  const int widx = bid >> 3, head = bid & 7;
  const int tid = threadIdx.x;
  const size_t base = (size_t)bid * 12544;
  const int tb = (widx >> 6) & 1;
  const int hb = (((widx >> 3) & 7) == 7) ? 1 : 0;
  const int wb = ((widx & 7) == 7) ? 1 : 0;
  const int sl = (tb * 4 + hb * 2 + wb) * 8 + head;
  const int VOFF = 25088;

  // --- stage K rows 0..383 via global_load_lds (pre-swizzled source)
  for (int i = 0; i < 6; i++) {
    int s = i * 256 + tid;  // slot: row=s>>2, cslot=s&3
    int r = s >> 2, cs = s & 3;
    gload_lds16(kg + base + r * 32 + ((cs ^ ((r >> 1) & 3)) << 3),
                (u16*)(lds + (size_t)(i * 256 + (tid & ~63)) * 16));
  }
  // rows 384..391 manually (tail)
  {
    int r = 384 + (tid >> 5), e = tid & 31;
    *(u16*)(lds + r * 64 + e * 2) =
        kg[base + r * 32 + (((e >> 3) ^ ((r >> 1) & 3)) << 3) + (e & 7)];
  }
  // --- stage V^T rows (coalesced), zero pad cols 400..415
  {
    const u16* vsrc = vTg + (size_t)bid * 12800;
    for (int idx = tid; idx < 3200; idx += 256) {
      int d = idx / 100, c4 = idx - d * 100;
      *(ushort4*)(lds + VOFF + d * 848 + c4 * 8) =
          *(const ushort4*)(vsrc + d * 400 + c4 * 4);
    }
    for (int idx = tid; idx < 512; idx += 256) {
      int d = idx >> 4, e = idx & 15;
      *(u16*)(lds + VOFF + d * 848 + 800 + e * 2) = 0;
    }
  }
  __syncthreads();

  const int w = tid >> 6, lane = tid & 63;
  const int g = lane >> 4, lm = lane & 15;
  char* PqW = lds + 52224 + w * 2048 + lm * 128;
  const int swz = (lm & 7) << 4;
  const int kswz = ((lm >> 1) & 3);

  for (int qt = w; qt < 25; qt += 4) {
    const int q = qt * 16 + lm;
    const int qr = q < 391 ? q : 391;
    bf16x8 qf = *(const bf16x8*)(qg + base + (size_t)qr * 32 + g * 8);
    const u16* bp = biasM + ((size_t)(sl * 392 + qr)) * 400 + 4 * g;
    const float rmb = rowmax[sl * 392 + qr];
    f32x4 st[25];
#pragma unroll
    for (int t = 0; t < 25; t++) {
      bf16x8 kf = *(const bf16x8*)(lds + (16 * t + lm) * 64 + ((g ^ kswz) << 4));
      st[t] = __builtin_amdgcn_mfma_f32_16x16x32_bf16(
          kf, qf, (f32x4){0.f, 0.f, 0.f, 0.f}, 0, 0, 0);
    }
#pragma unroll
    for (int t = 0; t < 25; t++) {
      ushort4 bb = *(const ushort4*)(bp + 16 * t);
      st[t][0] += b2f(bb.x);
      st[t][1] += b2f(bb.y);
      st[t][2] += b2f(bb.z);
      st[t][3] += b2f(bb.w);
    }
    float m = -3e38f;
#pragma unroll
    for (int t = 0; t < 25; t++)
      m = fmaxf(m, fmaxf(fmaxf(st[t][0], st[t][1]), fmaxf(st[t][2], st[t][3])));
    m = fmaxf(m, __shfl_xor(m, 16, 64));
    m = fmaxf(m, __shfl_xor(m, 32, 64));
    m += rmb;  // upper bound of max(S + bias)

    float sum = 0.f;
    f32x4 oa0 = {0.f, 0.f, 0.f, 0.f}, oa1 = {0.f, 0.f, 0.f, 0.f};
#pragma unroll
    for (int p = 0; p < 6; p++) {
#pragma unroll
      for (int tl = 0; tl < 4; tl++) {
        int t = 4 * p + tl;
        float e0 = vexp2(st[t][0] - m), e1 = vexp2(st[t][1] - m);
        float e2 = vexp2(st[t][2] - m), e3 = vexp2(st[t][3] - m);
        sum += (e0 + e1) + (e2 + e3);
        uint2 pp;
        pp.x = cvtpk(e0, e1);
        pp.y = cvtpk(e2, e3);
        *(uint2*)(PqW + ((32 * tl + 8 * g) ^ swz)) = pp;
      }
      asm volatile("s_waitcnt lgkmcnt(0)" ::: "memory");
      __builtin_amdgcn_sched_barrier(0);
#pragma unroll
      for (int cl = 0; cl < 2; cl++) {
        int c = 2 * p + cl;
        bf16x8 pf = *(const bf16x8*)(PqW + ((64 * cl + 16 * g) ^ swz));
        const char* vrow = lds + VOFF + 64 * c + 16 * g;
        bf16x8 v0 = *(const bf16x8*)(vrow + lm * 848);
        bf16x8 v1 = *(const bf16x8*)(vrow + (16 + lm) * 848);
        oa0 = __builtin_amdgcn_mfma_f32_16x16x32_bf16(pf, v0, oa0, 0, 0, 0);
        oa1 = __builtin_amdgcn_mfma_f32_16x16x32_bf16(pf, v1, oa1, 0, 0, 0);
      }
      __builtin_amdgcn_sched_barrier(0);
    }
    {  // pass 6: tile 24 real + zero tile, chunk 12
      float e0 = vexp2(st[24][0] - m), e1 = vexp2(st[24][1] - m);
      float e2 = vexp2(st[24][2] - m), e3 = vexp2(st[24][3] - m);
      sum += (e0 + e1) + (e2 + e3);
      uint2 pp;
      pp.x = cvtpk(e0, e1);
      pp.y = cvtpk(e2, e3);
      *(uint2*)(PqW + ((8 * g) ^ swz)) = pp;
      uint2 zz; zz.x = 0u; zz.y = 0u;
      *(uint2*)(PqW + ((32 + 8 * g) ^ swz)) = zz;
      asm volatile("s_waitcnt lgkmcnt(0)" ::: "memory");
      __builtin_amdgcn_sched_barrier(0);
      bf16x8 pf = *(const bf16x8*)(PqW + ((16 * g) ^ swz));
      const char* vrow = lds + VOFF + 64 * 12 + 16 * g;
      bf16x8 v0 = *(const bf16x8*)(vrow + lm * 848);
      bf16x8 v1 = *(const bf16x8*)(vrow + (16 + lm) * 848);
      oa0 = __builtin_amdgcn_mfma_f32_16x16x32_bf16(pf, v0, oa0, 0, 0, 0);
      oa1 = __builtin_amdgcn_mfma_f32_16x16x32_bf16(pf, v1, oa1, 0, 0, 0);
      __builtin_amdgcn_sched_barrier(0);
    }
    sum += __shfl_xor(sum, 16, 64);
    sum += __shfl_xor(sum, 32, 64);
    const float inv = 1.f / sum;
#pragma unroll
    for (int r = 0; r < 4; r++) {
      int qq = qt * 16 + 4 * g + r;
      if (qq < 392) {
        u16* op = attno + ((size_t)(widx * 392 + qq)) * 256 + head * 32;
        op[lm] = f2b(oa0[r] * inv);
        op[16 + lm] = f2b(oa1[r] * inv);
      }
    }
  }
}

extern "C" void kernel_launch(void* const* d_in, const int* in_sizes, int n_in,
                              void* d_out, int out_size, void* d_ws,
                              size_t ws_size, hipStream_t stream) {
  const float* x     = (const float*)d_in[0];
  const float* n1g   = (const float*)d_in[1];
  const float* n1b   = (const float*)d_in[2];
  const float* qkvw  = (const float*)d_in[3];
  const float* qkvb  = (const float*)d_in[4];
  const float* rpb   = (const float*)d_in[5];
  const float* projw = (const float*)d_in[6];
  const float* projb = (const float*)d_in[7];
  const float* n2g   = (const float*)d_in[8];
  const float* n2b   = (const float*)d_in[9];
  const float* fc1w  = (const float*)d_in[10];
  const float* fc1b  = (const float*)d_in[11];
  const float* fc2w  = (const float*)d_in[12];
  const float* fc2b  = (const float*)d_in[13];

  // Workspace (NEED = 130,547,712 B), lifetime-aliased:
  //  [0, 25.69M)            xw -> attno -> hid(low)
  //  [25.69M, 51.38M)       q            -> hid
  //  [51.38M, 77.07M)       k            -> hid
  //  [77.07M, 103.28M)      vT (26.21M)  -> hid(top)
  //  [103.28M, 128.97M)     biasM(20.07M)+rowmax(0.4M) -> h2 (25.69M)
  //  [128.97M, 130.55M)     bf16 weights
  // xres (fp32 residual) lives in d_out.
  const size_t NEED = 130547712;
  if (ws_size < NEED) return;

  char* ws = (char*)d_ws;
  u16* xw      = (u16*)(ws + 0LL);
  u16* qb      = (u16*)(ws + 25690112LL);
  u16* attno   = (u16*)(ws + 0LL);
  u16* hid     = (u16*)(ws + 0LL);
  u16* biasM   = (u16*)(ws + 103284736LL);
  float* rmx   = (float*)(ws + 123355136LL);
  u16* h2      = (u16*)(ws + 103284736LL);
  u16* wq      = (u16*)(ws + 128974848LL);
  u16* wp      = (u16*)(ws + 129368064LL);
  u16* w1      = (u16*)(ws + 129499136LL);
  u16* w2      = (u16*)(ws + 130023424LL);
  float* xres  = (float*)d_out;

  castw<<<768, 256, 0, stream>>>(qkvw, wq, 196608);
  castw<<<256, 256, 0, stream>>>(projw, wp, 65536);
  castw<<<1024, 256, 0, stream>>>(fc1w, w1, 262144);
  castw<<<1024, 256, 0, stream>>>(fc2w, w2, 262144);
  bias_k<<<25088, 256, 0, stream>>>(rpb, biasM, rmx);

  ln_k<<<12544, 256, 0, stream>>>(x, n1g, n1b, xw, 1);
  gemm_k<0><<<392 * 6, 256, 0, stream>>>(
      xw, wq, 256, 6, qkvb, qb, nullptr, nullptr,
      0.17677669529663687f * 1.4426950408889634f);
  attn_k<<<1024, 256, 0, stream>>>(qb, qb + 12845056, qb + 2 * 12845056, biasM,
                                   rmx, attno);
  gemm_k<1><<<392 * 2, 256, 0, stream>>>(attno, wp, 256, 2, projb, nullptr,
                                         xres, x, 0.f);
  ln_k<<<12544, 256, 0, stream>>>(xres, n2g, n2b, h2, 0);
  gemm_k<2><<<392 * 8, 256, 0, stream>>>(h2, w1, 256, 8, fc1b, hid, nullptr,
                                         nullptr, 0.f);
  gemm_k<3><<<392 * 2, 256, 0, stream>>>(hid, w2, 1024, 2, fc2b, nullptr,
                                         (float*)d_out, xres, 0.f);
}

// Round 7
// 387.097 us; speedup vs baseline: 3.1702x; 1.0073x over previous
//
#include <hip/hip_runtime.h>
#include <hip/hip_bf16.h>
#include <cmath>

typedef unsigned short u16;
typedef unsigned int u32;

using bf16x8 = __attribute__((ext_vector_type(8))) short;
using f32x4  = __attribute__((ext_vector_type(4))) float;

__device__ __forceinline__ float b2f(u16 u) {
  union { u32 i; float f; } x; x.i = ((u32)u) << 16; return x.f;
}
__device__ __forceinline__ u16 f2b(float f) {
  union { float f; u32 i; } x; x.f = f;
  u32 r = x.i + 0x7fffu + ((x.i >> 16) & 1u);
  return (u16)(r >> 16);
}
__device__ __forceinline__ u32 cvtpk(float lo, float hi) {
  u32 r;
  asm("v_cvt_pk_bf16_f32 %0, %1, %2" : "=v"(r) : "v"(lo), "v"(hi));
  return r;
}
__device__ __forceinline__ float vexp2(float x) {
  float r;
  asm("v_exp_f32 %0, %1" : "=v"(r) : "v"(x));
  return r;
}
__device__ __forceinline__ void gload_lds16(const u16* g, u16* l) {
  __builtin_amdgcn_global_load_lds(
      (const __attribute__((address_space(1))) unsigned int*)g,
      (__attribute__((address_space(3))) unsigned int*)l, 16, 0, 0);
}

// ---------------- weight cast fp32 -> bf16 ----------------
__global__ __launch_bounds__(256) void castw(const float* __restrict__ a,
                                             u16* __restrict__ o, int n) {
  int i = blockIdx.x * 256 + threadIdx.x;
  if (i < n) o[i] = f2b(a[i]);
}

// ------- combined (bias+mask)*log2e table [8cls][8h][392][400] bf16 + rowmax
// grid 64*49; wave handles 2 rows (8 rows/block).
__global__ __launch_bounds__(256) void bias_k(const float* __restrict__ rpb,
                                              u16* __restrict__ biasM,
                                              float* __restrict__ rowmax) {
  const int b = blockIdx.x;  // sh*49 + rg
  const int sh = b / 49, rg = b - sh * 49;
  const int head = sh & 7, cls = sh >> 3;
  const int tb = (cls >> 2) & 1, hb = (cls >> 1) & 1, wb = cls & 1;
  const int w = threadIdx.x >> 6, lane = threadIdx.x & 63;
#pragma unroll
  for (int rr = 0; rr < 2; rr++) {
    const int q = rg * 8 + w * 2 + rr;
    const int ti = q / 49, rem = q - ti * 49, hi = rem / 7, wi = rem - hi * 7;
    const int cq = ti * 169 + hi * 13 + wi;
    const int rtq = tb ? (ti < 4 ? 1 : 2) : 0;
    const int rhq = hb ? (hi < 4 ? 1 : 2) : 0;
    const int rwq = wb ? (wi < 4 ? 1 : 2) : 0;
    const int labq = rtq * 9 + rhq * 3 + rwq;
    float mx = -3e38f;
    u16* orow = biasM + ((size_t)(sh * 392 + q)) * 400;
    for (int k = lane; k < 400; k += 64) {
      float v;
      if (k < 392) {
        int tk = k / 49, rk = k - tk * 49, hk = rk / 7, wk = rk - hk * 7;
        int ck = tk * 169 + hk * 13 + wk;
        float bv = rpb[(cq - ck + 1267) * 8 + head];
        int rt = tb ? (tk < 4 ? 1 : 2) : 0;
        int rh = hb ? (hk < 4 ? 1 : 2) : 0;
        int rw = wb ? (wk < 4 ? 1 : 2) : 0;
        if (rt * 9 + rh * 3 + rw != labq) bv -= 100.f;
        v = bv * 1.4426950408889634f;
        mx = fmaxf(mx, v);
      } else {
        v = -2081.f;  // pad keys: exp2 -> exactly 0
      }
      orow[k] = f2b(v);
    }
    for (int o = 1; o < 64; o <<= 1) mx = fmaxf(mx, __shfl_xor(mx, o, 64));
    if (lane == 0) rowmax[sh * 392 + q] = mx;
  }
}

// ---------------- LayerNorm (+ optional roll+window-partition gather) ------
__global__ __launch_bounds__(256) void ln_k(const float* __restrict__ src,
                                            const float* __restrict__ g,
                                            const float* __restrict__ b,
                                            u16* __restrict__ dst, int shifted) {
  const int wid = threadIdx.x >> 6, lane = threadIdx.x & 63;
  const int row = blockIdx.x * 4 + wid;
  int srow;
  if (shifted) {
    int widx = row / 392, n = row - widx * 392;
    int wt = widx >> 6, wh = (widx >> 3) & 7, ww = widx & 7;
    int ti = n / 49, rem = n - ti * 49, hi = rem / 7, wi = rem - hi * 7;
    int t = (wt * 8 + ti + 4) & 15;
    int h = wh * 7 + hi + 3; if (h >= 56) h -= 56;
    int w = ww * 7 + wi + 3; if (w >= 56) w -= 56;
    srow = (t * 56 + h) * 56 + w;
  } else {
    srow = row;
  }
  float4 v = *(const float4*)(src + (size_t)srow * 256 + lane * 4);
  float s = v.x + v.y + v.z + v.w;
  float sq = v.x * v.x + v.y * v.y + v.z * v.z + v.w * v.w;
  for (int o = 1; o < 64; o <<= 1) {
    s += __shfl_xor(s, o, 64);
    sq += __shfl_xor(sq, o, 64);
  }
  float mu = s * (1.0f / 256.0f);
  float rstd = rsqrtf(sq * (1.0f / 256.0f) - mu * mu + 1e-5f);
  float4 gg = *(const float4*)(g + lane * 4);
  float4 bb = *(const float4*)(b + lane * 4);
  ushort4 ov;
  ov.x = f2b((v.x - mu) * rstd * gg.x + bb.x);
  ov.y = f2b((v.y - mu) * rstd * gg.y + bb.y);
  ov.z = f2b((v.z - mu) * rstd * gg.z + bb.z);
  ov.w = f2b((v.w - mu) * rstd * gg.w + bb.w);
  *(ushort4*)(dst + (size_t)row * 256 + lane * 4) = ov;
}

// ---------------- MFMA GEMM: C = A(MxK) @ B(NxK)^T, M-tile TM x N-tile 128 -
// TM=128: 256 thr / 4 waves; TM=256: 512 thr / 8 waves. Per wave 64x64 out.
// global_load_lds staging, XOR-swizzle via pre-swizzled source (slot^row&7).
template <int EPI, int TM>
__global__ __launch_bounds__(TM * 2) void gemm_k(const u16* __restrict__ A,
                                                 const u16* __restrict__ Bw,
                                                 int K, int tilesN,
                                                 const float* __restrict__ bias,
                                                 u16* __restrict__ outb,
                                                 float* __restrict__ outf,
                                                 const float* __restrict__ res,
                                                 float qscale) {
  constexpr int NW = TM / 32;              // waves per block
  constexpr int JA = TM * 8 / (NW * 64);   // = 4
  constexpr int JB = 128 * 8 / (NW * 64);  // 4 (TM=128) / 2 (TM=256)
  __shared__ __align__(16) u16 As[TM * 64];
  __shared__ __align__(16) u16 Bs[128 * 64];
  const int tid = threadIdx.x;
  const int tm = blockIdx.x / tilesN, tn = blockIdx.x % tilesN;
  const int wid = tid >> 6, lane = tid & 63;
  const int wm = wid >> 1, wn = wid & 1;
  const int lm = lane & 15, lk = lane >> 4;
  f32x4 acc[4][4] = {};
  const u16* Ap = A + (size_t)tm * TM * K;
  const u16* Bp = Bw + (size_t)tn * 128 * K;

  for (int k0 = 0; k0 < K; k0 += 64) {
    __syncthreads();
#pragma unroll
    for (int j = 0; j < JA; j++) {
      int s = (j * NW + wid) * 64 + lane;
      int r = s >> 3, c8 = (s & 7) ^ (r & 7);
      gload_lds16(Ap + (size_t)r * K + k0 + c8 * 8,
                  As + (size_t)(j * NW + wid) * 512);
    }
#pragma unroll
    for (int j = 0; j < JB; j++) {
      int s = (j * NW + wid) * 64 + lane;
      int r = s >> 3, c8 = (s & 7) ^ (r & 7);
      gload_lds16(Bp + (size_t)r * K + k0 + c8 * 8,
                  Bs + (size_t)(j * NW + wid) * 512);
    }
    __syncthreads();
#pragma unroll
    for (int ks = 0; ks < 2; ks++) {
      bf16x8 af[4], bfr[4];
#pragma unroll
      for (int f = 0; f < 4; f++) {
        int ra = wm * 64 + f * 16 + lm;
        int rb = wn * 64 + f * 16 + lm;
        af[f] = *(const bf16x8*)((const char*)As + ra * 128 +
                                 (((ks * 4 + lk) ^ (ra & 7)) << 4));
        bfr[f] = *(const bf16x8*)((const char*)Bs + rb * 128 +
                                  (((ks * 4 + lk) ^ (rb & 7)) << 4));
      }
#pragma unroll
      for (int fm = 0; fm < 4; fm++)
#pragma unroll
        for (int fn = 0; fn < 4; fn++)
          acc[fm][fn] = __builtin_amdgcn_mfma_f32_16x16x32_bf16(
              af[fm], bfr[fn], acc[fm][fn], 0, 0, 0);
    }
  }
  const int rbase = tm * TM + wm * 64, cbase = tn * 128 + wn * 64;
#pragma unroll
  for (int fm = 0; fm < 4; fm++) {
#pragma unroll
    for (int fn = 0; fn < 4; fn++) {
      const int col = cbase + fn * 16 + lm;
#pragma unroll
      for (int r = 0; r < 4; r++) {
        const int row = rbase + fm * 16 + lk * 4 + r;
        float v = acc[fm][fn][r] + bias[col];
        if (EPI == 0) {
          int s = col >> 8, rem = col & 255, head = rem >> 5, d = rem & 31;
          int widx = row / 392, n = row - widx * 392;
          size_t o;
          if (s == 2) {
            o = 25690112u + (((size_t)(widx * 8 + head)) * 32 + d) * 400 + n;
          } else {
            if (s == 0) v *= qscale;
            o = (size_t)s * 12845056u +
                (((size_t)(widx * 8 + head)) * 392 + n) * 32 + d;
          }
          outb[o] = f2b(v);
        } else if (EPI == 1) {
          int widx = row / 392, n = row - widx * 392;
          int wt = widx >> 6, wh = (widx >> 3) & 7, ww = widx & 7;
          int ti = n / 49, rem2 = n - ti * 49, hi = rem2 / 7, wi = rem2 - hi * 7;
          int t = (wt * 8 + ti + 4) & 15;
          int h = wh * 7 + hi + 3; if (h >= 56) h -= 56;
          int w = ww * 7 + wi + 3; if (w >= 56) w -= 56;
          size_t dr = ((size_t)(t * 56 + h)) * 56 + w;
          outf[dr * 256 + col] = res[dr * 256 + col] + v;
        } else if (EPI == 2) {
          float gv = 0.5f * v * (1.0f + erff(v * 0.70710678f));
          outb[(size_t)row * 1024 + col] = f2b(gv);
        } else {
          outf[(size_t)row * 256 + col] = res[(size_t)row * 256 + col] + v;
        }
      }
    }
  }
}

// ---------------- MFMA windowed attention, block per (window, head) -------
// 384 threads / 6 waves. LDS: K [392][64B swz] @0 (25088) + V^T [32][848]
// @25088 (27136) + Pq 6x2048 @52224 -> 64512 B (2 blocks/CU, 3 waves/SIMD).
__global__ __launch_bounds__(384) void attn_k(const u16* __restrict__ qg,
                                              const u16* __restrict__ kg,
                                              const u16* __restrict__ vTg,
                                              const u16* __restrict__ biasM,
                                              const float* __restrict__ rowmax,
                                              u16* __restrict__ attno) {
  __shared__ __align__(16) char lds[64512];
  const int bid = blockIdx.x;  // widx*8 + head
  const int widx = bid >> 3, head = bid & 7;
  const int tid = threadIdx.x;
  const size_t base = (size_t)bid * 12544;
  const int tb = (widx >> 6) & 1;
  const int hb = (((widx >> 3) & 7) == 7) ? 1 : 0;
  const int wb = ((widx & 7) == 7) ? 1 : 0;
  const int sl = (tb * 4 + hb * 2 + wb) * 8 + head;
  const int VOFF = 25088;

  // --- stage K (1568 16B-slots) via global_load_lds, pre-swizzled source
#pragma unroll
  for (int i = 0; i < 4; i++) {
    int s = i * 384 + tid, r = s >> 2, cs = s & 3;
    gload_lds16(kg + base + r * 32 + ((cs ^ ((r >> 1) & 3)) << 3),
                (u16*)(lds + (size_t)(i * 384 + (tid & ~63)) * 16));
  }
  if (tid < 32) {
    int s = 1536 + tid, r = s >> 2, cs = s & 3;
    gload_lds16(kg + base + r * 32 + ((cs ^ ((r >> 1) & 3)) << 3),
                (u16*)(lds + (size_t)1536 * 16));
  }
  // --- stage V^T rows (coalesced), zero pad cols 400..415
  {
    const u16* vsrc = vTg + (size_t)bid * 12800;
    for (int idx = tid; idx < 3200; idx += 384) {
      int d = idx / 100, c4 = idx - d * 100;
      *(ushort4*)(lds + VOFF + d * 848 + c4 * 8) =
          *(const ushort4*)(vsrc + d * 400 + c4 * 4);
    }
    for (int idx = tid; idx < 512; idx += 384) {
      int d = idx >> 4, e = idx & 15;
      *(u16*)(lds + VOFF + d * 848 + 800 + e * 2) = 0;
    }
  }
  __syncthreads();

  const int w = tid >> 6, lane = tid & 63;
  const int g = lane >> 4, lm = lane & 15;
  char* PqW = lds + 52224 + w * 2048 + lm * 128;
  const int swz = (lm & 7) << 4;
  const int kswz = ((lm >> 1) & 3);

  for (int qt = w; qt < 25; qt += 6) {
    const int q = qt * 16 + lm;
    const int qr = q < 391 ? q : 391;
    bf16x8 qf = *(const bf16x8*)(qg + base + (size_t)qr * 32 + g * 8);
    const u16* bp = biasM + ((size_t)(sl * 392 + qr)) * 400 + 4 * g;
    const float rmb = rowmax[sl * 392 + qr];
    f32x4 st[25];
#pragma unroll
    for (int t = 0; t < 25; t++) {
      bf16x8 kf = *(const bf16x8*)(lds + (16 * t + lm) * 64 + ((g ^ kswz) << 4));
      st[t] = __builtin_amdgcn_mfma_f32_16x16x32_bf16(
          kf, qf, (f32x4){0.f, 0.f, 0.f, 0.f}, 0, 0, 0);
    }
#pragma unroll
    for (int t = 0; t < 25; t++) {
      ushort4 bb = *(const ushort4*)(bp + 16 * t);
      st[t][0] += b2f(bb.x);
      st[t][1] += b2f(bb.y);
      st[t][2] += b2f(bb.z);
      st[t][3] += b2f(bb.w);
    }
    float m = -3e38f;
#pragma unroll
    for (int t = 0; t < 25; t++)
      m = fmaxf(m, fmaxf(fmaxf(st[t][0], st[t][1]), fmaxf(st[t][2], st[t][3])));
    m = fmaxf(m, __shfl_xor(m, 16, 64));
    m = fmaxf(m, __shfl_xor(m, 32, 64));
    m += rmb;  // upper bound of max(S + bias)

    float sum = 0.f;
    f32x4 oa0 = {0.f, 0.f, 0.f, 0.f}, oa1 = {0.f, 0.f, 0.f, 0.f};
#pragma unroll
    for (int p = 0; p < 6; p++) {
#pragma unroll
      for (int tl = 0; tl < 4; tl++) {
        int t = 4 * p + tl;
        float e0 = vexp2(st[t][0] - m), e1 = vexp2(st[t][1] - m);
        float e2 = vexp2(st[t][2] - m), e3 = vexp2(st[t][3] - m);
        sum += (e0 + e1) + (e2 + e3);
        uint2 pp;
        pp.x = cvtpk(e0, e1);
        pp.y = cvtpk(e2, e3);
        *(uint2*)(PqW + ((32 * tl + 8 * g) ^ swz)) = pp;
      }
      asm volatile("s_waitcnt lgkmcnt(0)" ::: "memory");
      __builtin_amdgcn_sched_barrier(0);
#pragma unroll
      for (int cl = 0; cl < 2; cl++) {
        int c = 2 * p + cl;
        bf16x8 pf = *(const bf16x8*)(PqW + ((64 * cl + 16 * g) ^ swz));
        const char* vrow = lds + VOFF + 64 * c + 16 * g;
        bf16x8 v0 = *(const bf16x8*)(vrow + lm * 848);
        bf16x8 v1 = *(const bf16x8*)(vrow + (16 + lm) * 848);
        oa0 = __builtin_amdgcn_mfma_f32_16x16x32_bf16(pf, v0, oa0, 0, 0, 0);
        oa1 = __builtin_amdgcn_mfma_f32_16x16x32_bf16(pf, v1, oa1, 0, 0, 0);
      }
      __builtin_amdgcn_sched_barrier(0);
    }
    {  // pass 6: tile 24 real + zero tile, chunk 12
      float e0 = vexp2(st[24][0] - m), e1 = vexp2(st[24][1] - m);
      float e2 = vexp2(st[24][2] - m), e3 = vexp2(st[24][3] - m);
      sum += (e0 + e1) + (e2 + e3);
      uint2 pp;
      pp.x = cvtpk(e0, e1);
      pp.y = cvtpk(e2, e3);
      *(uint2*)(PqW + ((8 * g) ^ swz)) = pp;
      uint2 zz; zz.x = 0u; zz.y = 0u;
      *(uint2*)(PqW + ((32 + 8 * g) ^ swz)) = zz;
      asm volatile("s_waitcnt lgkmcnt(0)" ::: "memory");
      __builtin_amdgcn_sched_barrier(0);
      bf16x8 pf = *(const bf16x8*)(PqW + ((16 * g) ^ swz));
      const char* vrow = lds + VOFF + 64 * 12 + 16 * g;
      bf16x8 v0 = *(const bf16x8*)(vrow + lm * 848);
      bf16x8 v1 = *(const bf16x8*)(vrow + (16 + lm) * 848);
      oa0 = __builtin_amdgcn_mfma_f32_16x16x32_bf16(pf, v0, oa0, 0, 0, 0);
      oa1 = __builtin_amdgcn_mfma_f32_16x16x32_bf16(pf, v1, oa1, 0, 0, 0);
      __builtin_amdgcn_sched_barrier(0);
    }
    sum += __shfl_xor(sum, 16, 64);
    sum += __shfl_xor(sum, 32, 64);
    const float inv = 1.f / sum;
#pragma unroll
    for (int r = 0; r < 4; r++) {
      int qq = qt * 16 + 4 * g + r;
      if (qq < 392) {
        u16* op = attno + ((size_t)(widx * 392 + qq)) * 256 + head * 32;
        op[lm] = f2b(oa0[r] * inv);
        op[16 + lm] = f2b(oa1[r] * inv);
      }
    }
  }
}

extern "C" void kernel_launch(void* const* d_in, const int* in_sizes, int n_in,
                              void* d_out, int out_size, void* d_ws,
                              size_t ws_size, hipStream_t stream) {
  const float* x     = (const float*)d_in[0];
  const float* n1g   = (const float*)d_in[1];
  const float* n1b   = (const float*)d_in[2];
  const float* qkvw  = (const float*)d_in[3];
  const float* qkvb  = (const float*)d_in[4];
  const float* rpb   = (const float*)d_in[5];
  const float* projw = (const float*)d_in[6];
  const float* projb = (const float*)d_in[7];
  const float* n2g   = (const float*)d_in[8];
  const float* n2b   = (const float*)d_in[9];
  const float* fc1w  = (const float*)d_in[10];
  const float* fc1b  = (const float*)d_in[11];
  const float* fc2w  = (const float*)d_in[12];
  const float* fc2b  = (const float*)d_in[13];

  // Workspace (NEED = 130,547,712 B), lifetime-aliased:
  //  [0, 25.69M)            xw -> attno -> hid(low)
  //  [25.69M, 51.38M)       q            -> hid
  //  [51.38M, 77.07M)       k            -> hid
  //  [77.07M, 103.28M)      vT (26.21M)  -> hid(top)
  //  [103.28M, 128.97M)     biasM(20.07M)+rowmax(0.4M) -> h2 (25.69M)
  //  [128.97M, 130.55M)     bf16 weights
  // xres (fp32 residual) lives in d_out.
  const size_t NEED = 130547712;
  if (ws_size < NEED) return;

  char* ws = (char*)d_ws;
  u16* xw      = (u16*)(ws + 0LL);
  u16* qb      = (u16*)(ws + 25690112LL);
  u16* attno   = (u16*)(ws + 0LL);
  u16* hid     = (u16*)(ws + 0LL);
  u16* biasM   = (u16*)(ws + 103284736LL);
  float* rmx   = (float*)(ws + 123355136LL);
  u16* h2      = (u16*)(ws + 103284736LL);
  u16* wq      = (u16*)(ws + 128974848LL);
  u16* wp      = (u16*)(ws + 129368064LL);
  u16* w1      = (u16*)(ws + 129499136LL);
  u16* w2      = (u16*)(ws + 130023424LL);
  float* xres  = (float*)d_out;

  castw<<<768, 256, 0, stream>>>(qkvw, wq, 196608);
  castw<<<256, 256, 0, stream>>>(projw, wp, 65536);
  castw<<<1024, 256, 0, stream>>>(fc1w, w1, 262144);
  castw<<<1024, 256, 0, stream>>>(fc2w, w2, 262144);
  bias_k<<<3136, 256, 0, stream>>>(rpb, biasM, rmx);

  ln_k<<<12544, 256, 0, stream>>>(x, n1g, n1b, xw, 1);
  gemm_k<0, 256><<<196 * 6, 512, 0, stream>>>(
      xw, wq, 256, 6, qkvb, qb, nullptr, nullptr,
      0.17677669529663687f * 1.4426950408889634f);
  attn_k<<<1024, 384, 0, stream>>>(qb, qb + 12845056, qb + 2 * 12845056, biasM,
                                   rmx, attno);
  gemm_k<1, 128><<<392 * 2, 256, 0, stream>>>(attno, wp, 256, 2, projb,
                                              nullptr, xres, x, 0.f);
  ln_k<<<12544, 256, 0, stream>>>(xres, n2g, n2b, h2, 0);
  gemm_k<2, 256><<<196 * 8, 512, 0, stream>>>(h2, w1, 256, 8, fc1b, hid,
                                              nullptr, nullptr, 0.f);
  gemm_k<3, 128><<<392 * 2, 256, 0, stream>>>(hid, w2, 1024, 2, fc2b, nullptr,
                                              (float*)d_out, xres, 0.f);
}

// Round 8
// 350.063 us; speedup vs baseline: 3.5056x; 1.1058x over previous
//
#include <hip/hip_runtime.h>
#include <hip/hip_bf16.h>
#include <cmath>

typedef unsigned short u16;
typedef unsigned int u32;

using bf16x8 = __attribute__((ext_vector_type(8))) short;
using f32x4  = __attribute__((ext_vector_type(4))) float;

__device__ __forceinline__ float b2f(u16 u) {
  union { u32 i; float f; } x; x.i = ((u32)u) << 16; return x.f;
}
__device__ __forceinline__ u16 f2b(float f) {
  union { float f; u32 i; } x; x.f = f;
  u32 r = x.i + 0x7fffu + ((x.i >> 16) & 1u);
  return (u16)(r >> 16);
}
__device__ __forceinline__ u32 cvtpk(float lo, float hi) {
  u32 r;
  asm("v_cvt_pk_bf16_f32 %0, %1, %2" : "=v"(r) : "v"(lo), "v"(hi));
  return r;
}
__device__ __forceinline__ float vexp2(float x) {
  float r;
  asm("v_exp_f32 %0, %1" : "=v"(r) : "v"(x));
  return r;
}
__device__ __forceinline__ void gload_lds16(const u16* g, u16* l) {
  __builtin_amdgcn_global_load_lds(
      (const __attribute__((address_space(1))) unsigned int*)g,
      (__attribute__((address_space(3))) unsigned int*)l, 16, 0, 0);
}

// ---------------- weight cast fp32 -> bf16 ----------------
__global__ __launch_bounds__(256) void castw(const float* __restrict__ a,
                                             u16* __restrict__ o, int n) {
  int i = blockIdx.x * 256 + threadIdx.x;
  if (i < n) o[i] = f2b(a[i]);
}

// ------- combined (bias+mask)*log2e, tile-blocked [64 sl][25 qt][25 t][16 lm]
// [16 kloc] bf16 (one contiguous 512B tile per wave read) + per-row max.
// grid 1600 = 64*25; thread tid = lm*16+kl, loops over t.
__global__ __launch_bounds__(256) void bias_k(const float* __restrict__ rpb,
                                              u16* __restrict__ biasB,
                                              float* __restrict__ rowmax) {
  const int b = blockIdx.x;  // sl*25 + qt
  const int sl = b / 25, qt = b - sl * 25;
  const int head = sl & 7, cls = sl >> 3;
  const int tb = (cls >> 2) & 1, hb = (cls >> 1) & 1, wb = cls & 1;
  const int tid = threadIdx.x;
  const int lm = tid >> 4, kl = tid & 15;
  int q = qt * 16 + lm; if (q > 391) q = 391;
  const int ti = q / 49, rem = q - ti * 49, hi = rem / 7, wi = rem - hi * 7;
  const int cq = ti * 169 + hi * 13 + wi;
  const int rtq = tb ? (ti < 4 ? 1 : 2) : 0;
  const int rhq = hb ? (hi < 4 ? 1 : 2) : 0;
  const int rwq = wb ? (wi < 4 ? 1 : 2) : 0;
  const int labq = rtq * 9 + rhq * 3 + rwq;
  float mx = -3e38f;
  u16* ob = biasB + (size_t)b * 6400 + tid;
  for (int t = 0; t < 25; t++) {
    int k = t * 16 + kl;
    float v;
    if (k < 392) {
      int tk = k / 49, rk = k - tk * 49, hk = rk / 7, wk = rk - hk * 7;
      int ck = tk * 169 + hk * 13 + wk;
      float bv = rpb[(cq - ck + 1267) * 8 + head];
      int rt = tb ? (tk < 4 ? 1 : 2) : 0;
      int rh = hb ? (hk < 4 ? 1 : 2) : 0;
      int rw = wb ? (wk < 4 ? 1 : 2) : 0;
      if (rt * 9 + rh * 3 + rw != labq) bv -= 100.f;
      v = bv * 1.4426950408889634f;
      mx = fmaxf(mx, v);
    } else {
      v = -2081.f;  // pad keys: exp2 -> exactly 0
    }
    ob[t * 256] = f2b(v);
  }
  // reduce over kl (lane bits 0..3)
  mx = fmaxf(mx, __shfl_xor(mx, 1, 64));
  mx = fmaxf(mx, __shfl_xor(mx, 2, 64));
  mx = fmaxf(mx, __shfl_xor(mx, 4, 64));
  mx = fmaxf(mx, __shfl_xor(mx, 8, 64));
  if (kl == 0) rowmax[sl * 392 + q] = mx;
}

// ---------------- LayerNorm (+ optional roll+window-partition gather) ------
__global__ __launch_bounds__(256) void ln_k(const float* __restrict__ src,
                                            const float* __restrict__ g,
                                            const float* __restrict__ b,
                                            u16* __restrict__ dst, int shifted) {
  const int wid = threadIdx.x >> 6, lane = threadIdx.x & 63;
  const int row = blockIdx.x * 4 + wid;
  int srow;
  if (shifted) {
    int widx = row / 392, n = row - widx * 392;
    int wt = widx >> 6, wh = (widx >> 3) & 7, ww = widx & 7;
    int ti = n / 49, rem = n - ti * 49, hi = rem / 7, wi = rem - hi * 7;
    int t = (wt * 8 + ti + 4) & 15;
    int h = wh * 7 + hi + 3; if (h >= 56) h -= 56;
    int w = ww * 7 + wi + 3; if (w >= 56) w -= 56;
    srow = (t * 56 + h) * 56 + w;
  } else {
    srow = row;
  }
  float4 v = *(const float4*)(src + (size_t)srow * 256 + lane * 4);
  float s = v.x + v.y + v.z + v.w;
  float sq = v.x * v.x + v.y * v.y + v.z * v.z + v.w * v.w;
  for (int o = 1; o < 64; o <<= 1) {
    s += __shfl_xor(s, o, 64);
    sq += __shfl_xor(sq, o, 64);
  }
  float mu = s * (1.0f / 256.0f);
  float rstd = rsqrtf(sq * (1.0f / 256.0f) - mu * mu + 1e-5f);
  float4 gg = *(const float4*)(g + lane * 4);
  float4 bb = *(const float4*)(b + lane * 4);
  ushort4 ov;
  ov.x = f2b((v.x - mu) * rstd * gg.x + bb.x);
  ov.y = f2b((v.y - mu) * rstd * gg.y + bb.y);
  ov.z = f2b((v.z - mu) * rstd * gg.z + bb.z);
  ov.w = f2b((v.w - mu) * rstd * gg.w + bb.w);
  *(ushort4*)(dst + (size_t)row * 256 + lane * 4) = ov;
}

// ---------------- MFMA GEMM: C = A(MxK) @ B(NxK)^T, M-tile TM x N-tile 128 -
// XCD-bijective block swizzle (grid always divisible by 8).
template <int EPI, int TM>
__global__ __launch_bounds__(TM * 2) void gemm_k(const u16* __restrict__ A,
                                                 const u16* __restrict__ Bw,
                                                 int K, int tilesN,
                                                 const float* __restrict__ bias,
                                                 u16* __restrict__ outb,
                                                 float* __restrict__ outf,
                                                 const float* __restrict__ res,
                                                 float qscale) {
  constexpr int NW = TM / 32;              // waves per block
  constexpr int JA = TM * 8 / (NW * 64);   // = 4
  constexpr int JB = 128 * 8 / (NW * 64);  // 4 (TM=128) / 2 (TM=256)
  __shared__ __align__(16) u16 As[TM * 64];
  __shared__ __align__(16) u16 Bs[128 * 64];
  const int tid = threadIdx.x;
  const int swzb = ((int)blockIdx.x & 7) * ((int)gridDim.x >> 3) +
                   ((int)blockIdx.x >> 3);
  const int tm = swzb / tilesN, tn = swzb - tm * tilesN;
  const int wid = tid >> 6, lane = tid & 63;
  const int wm = wid >> 1, wn = wid & 1;
  const int lm = lane & 15, lk = lane >> 4;
  f32x4 acc[4][4] = {};
  const u16* Ap = A + (size_t)tm * TM * K;
  const u16* Bp = Bw + (size_t)tn * 128 * K;

  for (int k0 = 0; k0 < K; k0 += 64) {
    __syncthreads();
#pragma unroll
    for (int j = 0; j < JA; j++) {
      int s = (j * NW + wid) * 64 + lane;
      int r = s >> 3, c8 = (s & 7) ^ (r & 7);
      gload_lds16(Ap + (size_t)r * K + k0 + c8 * 8,
                  As + (size_t)(j * NW + wid) * 512);
    }
#pragma unroll
    for (int j = 0; j < JB; j++) {
      int s = (j * NW + wid) * 64 + lane;
      int r = s >> 3, c8 = (s & 7) ^ (r & 7);
      gload_lds16(Bp + (size_t)r * K + k0 + c8 * 8,
                  Bs + (size_t)(j * NW + wid) * 512);
    }
    __syncthreads();
#pragma unroll
    for (int ks = 0; ks < 2; ks++) {
      bf16x8 af[4], bfr[4];
#pragma unroll
      for (int f = 0; f < 4; f++) {
        int ra = wm * 64 + f * 16 + lm;
        int rb = wn * 64 + f * 16 + lm;
        af[f] = *(const bf16x8*)((const char*)As + ra * 128 +
                                 (((ks * 4 + lk) ^ (ra & 7)) << 4));
        bfr[f] = *(const bf16x8*)((const char*)Bs + rb * 128 +
                                  (((ks * 4 + lk) ^ (rb & 7)) << 4));
      }
#pragma unroll
      for (int fm = 0; fm < 4; fm++)
#pragma unroll
        for (int fn = 0; fn < 4; fn++)
          acc[fm][fn] = __builtin_amdgcn_mfma_f32_16x16x32_bf16(
              af[fm], bfr[fn], acc[fm][fn], 0, 0, 0);
    }
  }
  const int rbase = tm * TM + wm * 64, cbase = tn * 128 + wn * 64;
#pragma unroll
  for (int fm = 0; fm < 4; fm++) {
#pragma unroll
    for (int fn = 0; fn < 4; fn++) {
      const int col = cbase + fn * 16 + lm;
#pragma unroll
      for (int r = 0; r < 4; r++) {
        const int row = rbase + fm * 16 + lk * 4 + r;
        float v = acc[fm][fn][r] + bias[col];
        if (EPI == 0) {
          int s = col >> 8, rem = col & 255, head = rem >> 5, d = rem & 31;
          int widx = row / 392, n = row - widx * 392;
          size_t o;
          if (s == 2) {
            o = 25690112u + (((size_t)(widx * 8 + head)) * 32 + d) * 400 + n;
          } else {
            if (s == 0) v *= qscale;
            o = (size_t)s * 12845056u +
                (((size_t)(widx * 8 + head)) * 392 + n) * 32 + d;
          }
          outb[o] = f2b(v);
        } else if (EPI == 1) {
          int widx = row / 392, n = row - widx * 392;
          int wt = widx >> 6, wh = (widx >> 3) & 7, ww = widx & 7;
          int ti = n / 49, rem2 = n - ti * 49, hi = rem2 / 7, wi = rem2 - hi * 7;
          int t = (wt * 8 + ti + 4) & 15;
          int h = wh * 7 + hi + 3; if (h >= 56) h -= 56;
          int w = ww * 7 + wi + 3; if (w >= 56) w -= 56;
          size_t dr = ((size_t)(t * 56 + h)) * 56 + w;
          outf[dr * 256 + col] = res[dr * 256 + col] + v;
        } else if (EPI == 2) {
          float gv = 0.5f * v * (1.0f + erff(v * 0.70710678f));
          outb[(size_t)row * 1024 + col] = f2b(gv);
        } else {
          outf[(size_t)row * 256 + col] = res[(size_t)row * 256 + col] + v;
        }
      }
    }
  }
}

// ---------------- MFMA windowed attention, block per (window, head) -------
// 256 threads / 4 waves. LDS: K [400 rows][64B swz, rows 392..399 zero] @0
// (25600) + V^T [32][848] @25600 (27136) + Pq 4x2048 @52736 -> 60928 B.
// Bias comes in as contiguous 512B tiles and feeds the MFMA accumulator.
__global__ __launch_bounds__(256) void attn_k(const u16* __restrict__ qg,
                                              const u16* __restrict__ kg,
                                              const u16* __restrict__ vTg,
                                              const u16* __restrict__ biasB,
                                              const float* __restrict__ rowmax,
                                              u16* __restrict__ attno) {
  __shared__ __align__(16) char lds[60928];
  const int bid = blockIdx.x;  // widx*8 + head
  const int widx = bid >> 3;
  const int tid = threadIdx.x;
  const size_t base = (size_t)bid * 12544;
  const int tb = (widx >> 6) & 1;
  const int hb = (((widx >> 3) & 7) == 7) ? 1 : 0;
  const int wb = ((widx & 7) == 7) ? 1 : 0;
  const int sl = (tb * 4 + hb * 2 + wb) * 8 + (bid & 7);
  const int VOFF = 25600;

  // --- stage K rows 0..391 via global_load_lds (pre-swizzled source)
#pragma unroll
  for (int i = 0; i < 6; i++) {
    int s = i * 256 + tid, r = s >> 2, cs = s & 3;
    gload_lds16(kg + base + r * 32 + ((cs ^ ((r >> 1) & 3)) << 3),
                (u16*)(lds + (size_t)(i * 256 + (tid & ~63)) * 16));
  }
  if (tid < 32) {
    int s = 1536 + tid, r = s >> 2, cs = s & 3;
    gload_lds16(kg + base + r * 32 + ((cs ^ ((r >> 1) & 3)) << 3),
                (u16*)(lds + (size_t)1536 * 16));
  }
  // zero K pad rows 392..399
  if (tid < 128) ((u32*)(lds + 25088))[tid] = 0u;
  // --- stage V^T rows (coalesced), zero pad cols 400..423
  {
    const u16* vsrc = vTg + (size_t)bid * 12800;
    for (int idx = tid; idx < 3200; idx += 256) {
      int d = idx / 100, c4 = idx - d * 100;
      *(ushort4*)(lds + VOFF + d * 848 + c4 * 8) =
          *(const ushort4*)(vsrc + d * 400 + c4 * 4);
    }
    for (int idx = tid; idx < 512; idx += 256) {
      int d = idx >> 4, e = idx & 15;
      *(u16*)(lds + VOFF + d * 848 + 800 + e * 2) = 0;
    }
  }
  __syncthreads();

  const int w = tid >> 6, lane = tid & 63;
  const int g = lane >> 4, lm = lane & 15;
  char* PqW = lds + 52736 + w * 2048 + lm * 128;
  const int swz = (lm & 7) << 4;
  const int kswz = ((lm >> 1) & 3);

  for (int qt = w; qt < 25; qt += 4) {
    const int q = qt * 16 + lm;
    const int qr = q < 391 ? q : 391;
    bf16x8 qf = *(const bf16x8*)(qg + base + (size_t)qr * 32 + g * 8);
    const u16* bp = biasB + ((size_t)(sl * 25 + qt) * 25) * 256 + lm * 16 + 4 * g;
    const float rmb = rowmax[sl * 392 + qr];
    f32x4 st[25];
#pragma unroll
    for (int t = 0; t < 25; t++) {
      ushort4 bb = *(const ushort4*)(bp + t * 256);
      f32x4 bacc = {b2f(bb.x), b2f(bb.y), b2f(bb.z), b2f(bb.w)};
      bf16x8 kf = *(const bf16x8*)(lds + (16 * t + lm) * 64 + ((g ^ kswz) << 4));
      st[t] = __builtin_amdgcn_mfma_f32_16x16x32_bf16(kf, qf, bacc, 0, 0, 0);
    }
    float m = -3e38f;
#pragma unroll
    for (int t = 0; t < 25; t++)
      m = fmaxf(m, fmaxf(fmaxf(st[t][0], st[t][1]), fmaxf(st[t][2], st[t][3])));
    m = fmaxf(m, __shfl_xor(m, 16, 64));
    m = fmaxf(m, __shfl_xor(m, 32, 64));
    m += rmb;  // upper bound of max(S + bias)

    float sum = 0.f;
    f32x4 oa0 = {0.f, 0.f, 0.f, 0.f}, oa1 = {0.f, 0.f, 0.f, 0.f};
#pragma unroll
    for (int p = 0; p < 6; p++) {
#pragma unroll
      for (int tl = 0; tl < 4; tl++) {
        int t = 4 * p + tl;
        float e0 = vexp2(st[t][0] - m), e1 = vexp2(st[t][1] - m);
        float e2 = vexp2(st[t][2] - m), e3 = vexp2(st[t][3] - m);
        sum += (e0 + e1) + (e2 + e3);
        uint2 pp;
        pp.x = cvtpk(e0, e1);
        pp.y = cvtpk(e2, e3);
        *(uint2*)(PqW + ((32 * tl + 8 * g) ^ swz)) = pp;
      }
      asm volatile("s_waitcnt lgkmcnt(0)" ::: "memory");
      __builtin_amdgcn_sched_barrier(0);
#pragma unroll
      for (int cl = 0; cl < 2; cl++) {
        int c = 2 * p + cl;
        bf16x8 pf = *(const bf16x8*)(PqW + ((64 * cl + 16 * g) ^ swz));
        const char* vrow = lds + VOFF + 64 * c + 16 * g;
        bf16x8 v0 = *(const bf16x8*)(vrow + lm * 848);
        bf16x8 v1 = *(const bf16x8*)(vrow + (16 + lm) * 848);
        oa0 = __builtin_amdgcn_mfma_f32_16x16x32_bf16(pf, v0, oa0, 0, 0, 0);
        oa1 = __builtin_amdgcn_mfma_f32_16x16x32_bf16(pf, v1, oa1, 0, 0, 0);
      }
      __builtin_amdgcn_sched_barrier(0);
    }
    {  // pass 6: tile 24 real + zero tile, chunk 12
      float e0 = vexp2(st[24][0] - m), e1 = vexp2(st[24][1] - m);
      float e2 = vexp2(st[24][2] - m), e3 = vexp2(st[24][3] - m);
      sum += (e0 + e1) + (e2 + e3);
      uint2 pp;
      pp.x = cvtpk(e0, e1);
      pp.y = cvtpk(e2, e3);
      *(uint2*)(PqW + ((8 * g) ^ swz)) = pp;
      uint2 zz; zz.x = 0u; zz.y = 0u;
      *(uint2*)(PqW + ((32 + 8 * g) ^ swz)) = zz;
      asm volatile("s_waitcnt lgkmcnt(0)" ::: "memory");
      __builtin_amdgcn_sched_barrier(0);
      bf16x8 pf = *(const bf16x8*)(PqW + ((16 * g) ^ swz));
      const char* vrow = lds + VOFF + 64 * 12 + 16 * g;
      bf16x8 v0 = *(const bf16x8*)(vrow + lm * 848);
      bf16x8 v1 = *(const bf16x8*)(vrow + (16 + lm) * 848);
      oa0 = __builtin_amdgcn_mfma_f32_16x16x32_bf16(pf, v0, oa0, 0, 0, 0);
      oa1 = __builtin_amdgcn_mfma_f32_16x16x32_bf16(pf, v1, oa1, 0, 0, 0);
      __builtin_amdgcn_sched_barrier(0);
    }
    sum += __shfl_xor(sum, 16, 64);
    sum += __shfl_xor(sum, 32, 64);
    const float inv = 1.f / sum;
#pragma unroll
    for (int r = 0; r < 4; r++) {
      int qq = qt * 16 + 4 * g + r;
      if (qq < 392) {
        u16* op = attno + ((size_t)(widx * 392 + qq)) * 256 + (bid & 7) * 32;
        op[lm] = f2b(oa0[r] * inv);
        op[16 + lm] = f2b(oa1[r] * inv);
      }
    }
  }
}

extern "C" void kernel_launch(void* const* d_in, const int* in_sizes, int n_in,
                              void* d_out, int out_size, void* d_ws,
                              size_t ws_size, hipStream_t stream) {
  const float* x     = (const float*)d_in[0];
  const float* n1g   = (const float*)d_in[1];
  const float* n1b   = (const float*)d_in[2];
  const float* qkvw  = (const float*)d_in[3];
  const float* qkvb  = (const float*)d_in[4];
  const float* rpb   = (const float*)d_in[5];
  const float* projw = (const float*)d_in[6];
  const float* projb = (const float*)d_in[7];
  const float* n2g   = (const float*)d_in[8];
  const float* n2b   = (const float*)d_in[9];
  const float* fc1w  = (const float*)d_in[10];
  const float* fc1b  = (const float*)d_in[11];
  const float* fc2w  = (const float*)d_in[12];
  const float* fc2b  = (const float*)d_in[13];

  // Workspace (NEED = 130,547,712 B), lifetime-aliased:
  //  [0, 25.69M)            xw -> attno -> hid(low)
  //  [25.69M, 51.38M)       q            -> hid
  //  [51.38M, 77.07M)       k            -> hid
  //  [77.07M, 103.28M)      vT (26.21M)  -> hid(top)
  //  [103.28M, 123.87M)     biasB(20.48M)+rowmax(0.1M) -> h2 (25.69M)
  //  [128.97M, 130.55M)     bf16 weights
  // xres (fp32 residual) lives in d_out.
  const size_t NEED = 130547712;
  if (ws_size < NEED) return;

  char* ws = (char*)d_ws;
  u16* xw      = (u16*)(ws + 0LL);
  u16* qb      = (u16*)(ws + 25690112LL);
  u16* attno   = (u16*)(ws + 0LL);
  u16* hid     = (u16*)(ws + 0LL);
  u16* biasB   = (u16*)(ws + 103284736LL);
  float* rmx   = (float*)(ws + 123764736LL);
  u16* h2      = (u16*)(ws + 103284736LL);
  u16* wq      = (u16*)(ws + 128974848LL);
  u16* wp      = (u16*)(ws + 129368064LL);
  u16* w1      = (u16*)(ws + 129499136LL);
  u16* w2      = (u16*)(ws + 130023424LL);
  float* xres  = (float*)d_out;

  castw<<<768, 256, 0, stream>>>(qkvw, wq, 196608);
  castw<<<256, 256, 0, stream>>>(projw, wp, 65536);
  castw<<<1024, 256, 0, stream>>>(fc1w, w1, 262144);
  castw<<<1024, 256, 0, stream>>>(fc2w, w2, 262144);
  bias_k<<<1600, 256, 0, stream>>>(rpb, biasB, rmx);

  ln_k<<<12544, 256, 0, stream>>>(x, n1g, n1b, xw, 1);
  gemm_k<0, 256><<<196 * 6, 512, 0, stream>>>(
      xw, wq, 256, 6, qkvb, qb, nullptr, nullptr,
      0.17677669529663687f * 1.4426950408889634f);
  attn_k<<<1024, 256, 0, stream>>>(qb, qb + 12845056, qb + 2 * 12845056, biasB,
                                   rmx, attno);
  gemm_k<1, 128><<<392 * 2, 256, 0, stream>>>(attno, wp, 256, 2, projb,
                                              nullptr, xres, x, 0.f);
  ln_k<<<12544, 256, 0, stream>>>(xres, n2g, n2b, h2, 0);
  gemm_k<2, 256><<<196 * 8, 512, 0, stream>>>(h2, w1, 256, 8, fc1b, hid,
                                              nullptr, nullptr, 0.f);
  gemm_k<3, 128><<<392 * 2, 256, 0, stream>>>(hid, w2, 1024, 2, fc2b, nullptr,
                                              (float*)d_out, xres, 0.f);
}

// Round 9
// 330.054 us; speedup vs baseline: 3.7181x; 1.0606x over previous
//
#include <hip/hip_runtime.h>
#include <hip/hip_bf16.h>
#include <cmath>

typedef unsigned short u16;
typedef unsigned int u32;

using bf16x8 = __attribute__((ext_vector_type(8))) short;
using f32x4  = __attribute__((ext_vector_type(4))) float;

__device__ __forceinline__ float b2f(u16 u) {
  union { u32 i; float f; } x; x.i = ((u32)u) << 16; return x.f;
}
__device__ __forceinline__ u16 f2b(float f) {
  union { float f; u32 i; } x; x.f = f;
  u32 r = x.i + 0x7fffu + ((x.i >> 16) & 1u);
  return (u16)(r >> 16);
}
__device__ __forceinline__ u32 cvtpk(float lo, float hi) {
  u32 r;
  asm("v_cvt_pk_bf16_f32 %0, %1, %2" : "=v"(r) : "v"(lo), "v"(hi));
  return r;
}
__device__ __forceinline__ float vexp2(float x) {
  float r;
  asm("v_exp_f32 %0, %1" : "=v"(r) : "v"(x));
  return r;
}
__device__ __forceinline__ void gload_lds16(const u16* g, u16* l) {
  __builtin_amdgcn_global_load_lds(
      (const __attribute__((address_space(1))) unsigned int*)g,
      (__attribute__((address_space(3))) unsigned int*)l, 16, 0, 0);
}

// ---------------- fused weight cast fp32 -> bf16 (outputs contiguous) -----
__global__ __launch_bounds__(256) void castw(const float* __restrict__ qkvw,
                                             const float* __restrict__ projw,
                                             const float* __restrict__ fc1w,
                                             const float* __restrict__ fc2w,
                                             u16* __restrict__ o) {
  int i = blockIdx.x * 256 + threadIdx.x;  // < 786432
  const float* src;
  int off;
  if (i < 196608)      { src = qkvw;  off = 0; }
  else if (i < 262144) { src = projw; off = 196608; }
  else if (i < 524288) { src = fc1w;  off = 262144; }
  else                 { src = fc2w;  off = 524288; }
  o[i] = f2b(src[i - off]);
}

// ------- combined (bias+mask)*log2e, tile-blocked [64 sl][25 qt][25 t][16 lm]
// [16 kloc] bf16 (one contiguous 512B tile per wave read) + per-row max.
__global__ __launch_bounds__(256) void bias_k(const float* __restrict__ rpb,
                                              u16* __restrict__ biasB,
                                              float* __restrict__ rowmax) {
  const int b = blockIdx.x;  // sl*25 + qt
  const int sl = b / 25, qt = b - sl * 25;
  const int head = sl & 7, cls = sl >> 3;
  const int tb = (cls >> 2) & 1, hb = (cls >> 1) & 1, wb = cls & 1;
  const int tid = threadIdx.x;
  const int lm = tid >> 4, kl = tid & 15;
  int q = qt * 16 + lm; if (q > 391) q = 391;
  const int ti = q / 49, rem = q - ti * 49, hi = rem / 7, wi = rem - hi * 7;
  const int cq = ti * 169 + hi * 13 + wi;
  const int rtq = tb ? (ti < 4 ? 1 : 2) : 0;
  const int rhq = hb ? (hi < 4 ? 1 : 2) : 0;
  const int rwq = wb ? (wi < 4 ? 1 : 2) : 0;
  const int labq = rtq * 9 + rhq * 3 + rwq;
  float mx = -3e38f;
  u16* ob = biasB + (size_t)b * 6400 + tid;
  for (int t = 0; t < 25; t++) {
    int k = t * 16 + kl;
    float v;
    if (k < 392) {
      int tk = k / 49, rk = k - tk * 49, hk = rk / 7, wk = rk - hk * 7;
      int ck = tk * 169 + hk * 13 + wk;
      float bv = rpb[(cq - ck + 1267) * 8 + head];
      int rt = tb ? (tk < 4 ? 1 : 2) : 0;
      int rh = hb ? (hk < 4 ? 1 : 2) : 0;
      int rw = wb ? (wk < 4 ? 1 : 2) : 0;
      if (rt * 9 + rh * 3 + rw != labq) bv -= 100.f;
      v = bv * 1.4426950408889634f;
      mx = fmaxf(mx, v);
    } else {
      v = -2081.f;  // pad keys: exp2 -> exactly 0
    }
    ob[t * 256] = f2b(v);
  }
  mx = fmaxf(mx, __shfl_xor(mx, 1, 64));
  mx = fmaxf(mx, __shfl_xor(mx, 2, 64));
  mx = fmaxf(mx, __shfl_xor(mx, 4, 64));
  mx = fmaxf(mx, __shfl_xor(mx, 8, 64));
  if (kl == 0) rowmax[sl * 392 + q] = mx;
}

// ---------------- LayerNorm (+ optional roll+window-partition gather) ------
__global__ __launch_bounds__(256) void ln_k(const float* __restrict__ src,
                                            const float* __restrict__ g,
                                            const float* __restrict__ b,
                                            u16* __restrict__ dst, int shifted) {
  const int wid = threadIdx.x >> 6, lane = threadIdx.x & 63;
  const int row = blockIdx.x * 4 + wid;
  int srow;
  if (shifted) {
    int widx = row / 392, n = row - widx * 392;
    int wt = widx >> 6, wh = (widx >> 3) & 7, ww = widx & 7;
    int ti = n / 49, rem = n - ti * 49, hi = rem / 7, wi = rem - hi * 7;
    int t = (wt * 8 + ti + 4) & 15;
    int h = wh * 7 + hi + 3; if (h >= 56) h -= 56;
    int w = ww * 7 + wi + 3; if (w >= 56) w -= 56;
    srow = (t * 56 + h) * 56 + w;
  } else {
    srow = row;
  }
  float4 v = *(const float4*)(src + (size_t)srow * 256 + lane * 4);
  float s = v.x + v.y + v.z + v.w;
  float sq = v.x * v.x + v.y * v.y + v.z * v.z + v.w * v.w;
  for (int o = 1; o < 64; o <<= 1) {
    s += __shfl_xor(s, o, 64);
    sq += __shfl_xor(sq, o, 64);
  }
  float mu = s * (1.0f / 256.0f);
  float rstd = rsqrtf(sq * (1.0f / 256.0f) - mu * mu + 1e-5f);
  float4 gg = *(const float4*)(g + lane * 4);
  float4 bb = *(const float4*)(b + lane * 4);
  ushort4 ov;
  ov.x = f2b((v.x - mu) * rstd * gg.x + bb.x);
  ov.y = f2b((v.y - mu) * rstd * gg.y + bb.y);
  ov.z = f2b((v.z - mu) * rstd * gg.z + bb.z);
  ov.w = f2b((v.w - mu) * rstd * gg.w + bb.w);
  *(ushort4*)(dst + (size_t)row * 256 + lane * 4) = ov;
}

// ---------------- MFMA GEMM: C = A(MxK) @ B(NxK)^T -----------------------
// TM=256 x BN=128, BK=32, 512 threads / 8 waves, double-buffered LDS (48KB),
// 2-phase: STAGE(next) issued BEFORE compute(cur), one drain+barrier per
// tile (guide T3 minimal template). Slot-XOR swizzle key (r>>1)&3 on both
// stage (pre-swizzled global source) and read -> 2-way residual (free).
template <int EPI>
__global__ __launch_bounds__(512) void gemm_k(const u16* __restrict__ A,
                                              const u16* __restrict__ Bw,
                                              int K, int tilesN,
                                              const float* __restrict__ bias,
                                              u16* __restrict__ outb,
                                              float* __restrict__ outf,
                                              const float* __restrict__ res,
                                              float qscale) {
  __shared__ __align__(16) u16 As[2][256 * 32];
  __shared__ __align__(16) u16 Bs[2][128 * 32];
  const int tid = threadIdx.x;
  const int swzb = ((int)blockIdx.x & 7) * ((int)gridDim.x >> 3) +
                   ((int)blockIdx.x >> 3);
  const int tm = swzb / tilesN, tn = swzb - tm * tilesN;
  const int wid = tid >> 6, lane = tid & 63;
  const int wm = wid >> 1, wn = wid & 1;
  const int lm = lane & 15, lk = lane >> 4;
  f32x4 acc[4][4] = {};
  const u16* Ap = A + (size_t)tm * 256 * K;
  const u16* Bp = Bw + (size_t)tn * 128 * K;

  // stage slot bases (wave-uniform) and per-lane pre-swizzled global offsets
  const int sA0 = wid * 128;          // 2 gloads: sA0, sA0+64
  const int sB0 = wid * 64;           // 1 gload
  const int nt = K >> 5;

#define STAGE(bufi, kk)                                                       \
  {                                                                           \
    int S = sA0 + lane, r = S >> 2, cs = S & 3;                               \
    gload_lds16(Ap + (size_t)r * K + (kk) + ((cs ^ ((r >> 1) & 3)) << 3),     \
                &As[bufi][sA0 * 8]);                                          \
    S = sA0 + 64 + lane; r = S >> 2; cs = S & 3;                              \
    gload_lds16(Ap + (size_t)r * K + (kk) + ((cs ^ ((r >> 1) & 3)) << 3),     \
                &As[bufi][(sA0 + 64) * 8]);                                   \
    S = sB0 + lane; r = S >> 2; cs = S & 3;                                   \
    gload_lds16(Bp + (size_t)r * K + (kk) + ((cs ^ ((r >> 1) & 3)) << 3),     \
                &Bs[bufi][sB0 * 8]);                                          \
  }

  STAGE(0, 0);
  __syncthreads();
  for (int t = 0; t < nt; t++) {
    const int cur = t & 1;
    if (t + 1 < nt) STAGE(cur ^ 1, (t + 1) << 5);
    bf16x8 af[4], bfr[4];
#pragma unroll
    for (int f = 0; f < 4; f++) {
      int ra = wm * 64 + f * 16 + lm;
      int rb = wn * 64 + f * 16 + lm;
      af[f] = *(const bf16x8*)((const char*)&As[cur][0] + ra * 64 +
                               ((lk ^ ((ra >> 1) & 3)) << 4));
      bfr[f] = *(const bf16x8*)((const char*)&Bs[cur][0] + rb * 64 +
                                ((lk ^ ((rb >> 1) & 3)) << 4));
    }
#pragma unroll
    for (int fm = 0; fm < 4; fm++)
#pragma unroll
      for (int fn = 0; fn < 4; fn++)
        acc[fm][fn] = __builtin_amdgcn_mfma_f32_16x16x32_bf16(
            af[fm], bfr[fn], acc[fm][fn], 0, 0, 0);
    __syncthreads();  // drains vmcnt (incl. prefetch) + lgkm, then barrier
  }
#undef STAGE

  const int rbase = tm * 256 + wm * 64, cbase = tn * 128 + wn * 64;
#pragma unroll
  for (int fm = 0; fm < 4; fm++) {
#pragma unroll
    for (int fn = 0; fn < 4; fn++) {
      const int col = cbase + fn * 16 + lm;
#pragma unroll
      for (int r = 0; r < 4; r++) {
        const int row = rbase + fm * 16 + lk * 4 + r;
        float v = acc[fm][fn][r] + bias[col];
        if (EPI == 0) {
          int s = col >> 8, rem = col & 255, head = rem >> 5, d = rem & 31;
          int widx = row / 392, n = row - widx * 392;
          size_t o;
          if (s == 2) {
            o = 25690112u + (((size_t)(widx * 8 + head)) * 32 + d) * 400 + n;
          } else {
            if (s == 0) v *= qscale;
            o = (size_t)s * 12845056u +
                (((size_t)(widx * 8 + head)) * 392 + n) * 32 + d;
          }
          outb[o] = f2b(v);
        } else if (EPI == 1) {
          int widx = row / 392, n = row - widx * 392;
          int wt = widx >> 6, wh = (widx >> 3) & 7, ww = widx & 7;
          int ti = n / 49, rem2 = n - ti * 49, hi = rem2 / 7, wi = rem2 - hi * 7;
          int t = (wt * 8 + ti + 4) & 15;
          int h = wh * 7 + hi + 3; if (h >= 56) h -= 56;
          int w = ww * 7 + wi + 3; if (w >= 56) w -= 56;
          size_t dr = ((size_t)(t * 56 + h)) * 56 + w;
          outf[dr * 256 + col] = res[dr * 256 + col] + v;
        } else if (EPI == 2) {
          float gv = 0.5f * v * (1.0f + erff(v * 0.70710678f));
          outb[(size_t)row * 1024 + col] = f2b(gv);
        } else {
          outf[(size_t)row * 256 + col] = res[(size_t)row * 256 + col] + v;
        }
      }
    }
  }
}

// ---------------- MFMA windowed attention, block per (window, head) -------
__global__ __launch_bounds__(256) void attn_k(const u16* __restrict__ qg,
                                              const u16* __restrict__ kg,
                                              const u16* __restrict__ vTg,
                                              const u16* __restrict__ biasB,
                                              const float* __restrict__ rowmax,
                                              u16* __restrict__ attno) {
  __shared__ __align__(16) char lds[60928];
  const int bid = blockIdx.x;  // widx*8 + head
  const int widx = bid >> 3;
  const int tid = threadIdx.x;
  const size_t base = (size_t)bid * 12544;
  const int tb = (widx >> 6) & 1;
  const int hb = (((widx >> 3) & 7) == 7) ? 1 : 0;
  const int wb = ((widx & 7) == 7) ? 1 : 0;
  const int sl = (tb * 4 + hb * 2 + wb) * 8 + (bid & 7);
  const int VOFF = 25600;

#pragma unroll
  for (int i = 0; i < 6; i++) {
    int s = i * 256 + tid, r = s >> 2, cs = s & 3;
    gload_lds16(kg + base + r * 32 + ((cs ^ ((r >> 1) & 3)) << 3),
                (u16*)(lds + (size_t)(i * 256 + (tid & ~63)) * 16));
  }
  if (tid < 32) {
    int s = 1536 + tid, r = s >> 2, cs = s & 3;
    gload_lds16(kg + base + r * 32 + ((cs ^ ((r >> 1) & 3)) << 3),
                (u16*)(lds + (size_t)1536 * 16));
  }
  if (tid < 128) ((u32*)(lds + 25088))[tid] = 0u;
  {
    const u16* vsrc = vTg + (size_t)bid * 12800;
    for (int idx = tid; idx < 3200; idx += 256) {
      int d = idx / 100, c4 = idx - d * 100;
      *(ushort4*)(lds + VOFF + d * 848 + c4 * 8) =
          *(const ushort4*)(vsrc + d * 400 + c4 * 4);
    }
    for (int idx = tid; idx < 512; idx += 256) {
      int d = idx >> 4, e = idx & 15;
      *(u16*)(lds + VOFF + d * 848 + 800 + e * 2) = 0;
    }
  }
  __syncthreads();

  const int w = tid >> 6, lane = tid & 63;
  const int g = lane >> 4, lm = lane & 15;
  char* PqW = lds + 52736 + w * 2048 + lm * 128;
  const int swz = (lm & 7) << 4;
  const int kswz = ((lm >> 1) & 3);

  for (int qt = w; qt < 25; qt += 4) {
    const int q = qt * 16 + lm;
    const int qr = q < 391 ? q : 391;
    bf16x8 qf = *(const bf16x8*)(qg + base + (size_t)qr * 32 + g * 8);
    const u16* bp = biasB + ((size_t)(sl * 25 + qt) * 25) * 256 + lm * 16 + 4 * g;
    const float rmb = rowmax[sl * 392 + qr];
    f32x4 st[25];
#pragma unroll
    for (int t = 0; t < 25; t++) {
      ushort4 bb = *(const ushort4*)(bp + t * 256);
      f32x4 bacc = {b2f(bb.x), b2f(bb.y), b2f(bb.z), b2f(bb.w)};
      bf16x8 kf = *(const bf16x8*)(lds + (16 * t + lm) * 64 + ((g ^ kswz) << 4));
      st[t] = __builtin_amdgcn_mfma_f32_16x16x32_bf16(kf, qf, bacc, 0, 0, 0);
    }
    float m = -3e38f;
#pragma unroll
    for (int t = 0; t < 25; t++)
      m = fmaxf(m, fmaxf(fmaxf(st[t][0], st[t][1]), fmaxf(st[t][2], st[t][3])));
    m = fmaxf(m, __shfl_xor(m, 16, 64));
    m = fmaxf(m, __shfl_xor(m, 32, 64));
    m += rmb;  // upper bound of max(S + bias)

    float sum = 0.f;
    f32x4 oa0 = {0.f, 0.f, 0.f, 0.f}, oa1 = {0.f, 0.f, 0.f, 0.f};
#pragma unroll
    for (int p = 0; p < 6; p++) {
#pragma unroll
      for (int tl = 0; tl < 4; tl++) {
        int t = 4 * p + tl;
        float e0 = vexp2(st[t][0] - m), e1 = vexp2(st[t][1] - m);
        float e2 = vexp2(st[t][2] - m), e3 = vexp2(st[t][3] - m);
        sum += (e0 + e1) + (e2 + e3);
        uint2 pp;
        pp.x = cvtpk(e0, e1);
        pp.y = cvtpk(e2, e3);
        *(uint2*)(PqW + ((32 * tl + 8 * g) ^ swz)) = pp;
      }
      asm volatile("s_waitcnt lgkmcnt(0)" ::: "memory");
      __builtin_amdgcn_sched_barrier(0);
#pragma unroll
      for (int cl = 0; cl < 2; cl++) {
        int c = 2 * p + cl;
        bf16x8 pf = *(const bf16x8*)(PqW + ((64 * cl + 16 * g) ^ swz));
        const char* vrow = lds + VOFF + 64 * c + 16 * g;
        bf16x8 v0 = *(const bf16x8*)(vrow + lm * 848);
        bf16x8 v1 = *(const bf16x8*)(vrow + (16 + lm) * 848);
        oa0 = __builtin_amdgcn_mfma_f32_16x16x32_bf16(pf, v0, oa0, 0, 0, 0);
        oa1 = __builtin_amdgcn_mfma_f32_16x16x32_bf16(pf, v1, oa1, 0, 0, 0);
      }
      __builtin_amdgcn_sched_barrier(0);
    }
    {  // pass 6: tile 24 real + zero tile, chunk 12
      float e0 = vexp2(st[24][0] - m), e1 = vexp2(st[24][1] - m);
      float e2 = vexp2(st[24][2] - m), e3 = vexp2(st[24][3] - m);
      sum += (e0 + e1) + (e2 + e3);
      uint2 pp;
      pp.x = cvtpk(e0, e1);
      pp.y = cvtpk(e2, e3);
      *(uint2*)(PqW + ((8 * g) ^ swz)) = pp;
      uint2 zz; zz.x = 0u; zz.y = 0u;
      *(uint2*)(PqW + ((32 + 8 * g) ^ swz)) = zz;
      asm volatile("s_waitcnt lgkmcnt(0)" ::: "memory");
      __builtin_amdgcn_sched_barrier(0);
      bf16x8 pf = *(const bf16x8*)(PqW + ((16 * g) ^ swz));
      const char* vrow = lds + VOFF + 64 * 12 + 16 * g;
      bf16x8 v0 = *(const bf16x8*)(vrow + lm * 848);
      bf16x8 v1 = *(const bf16x8*)(vrow + (16 + lm) * 848);
      oa0 = __builtin_amdgcn_mfma_f32_16x16x32_bf16(pf, v0, oa0, 0, 0, 0);
      oa1 = __builtin_amdgcn_mfma_f32_16x16x32_bf16(pf, v1, oa1, 0, 0, 0);
      __builtin_amdgcn_sched_barrier(0);
    }
    sum += __shfl_xor(sum, 16, 64);
    sum += __shfl_xor(sum, 32, 64);
    const float inv = 1.f / sum;
#pragma unroll
    for (int r = 0; r < 4; r++) {
      int qq = qt * 16 + 4 * g + r;
      if (qq < 392) {
        u16* op = attno + ((size_t)(widx * 392 + qq)) * 256 + (bid & 7) * 32;
        op[lm] = f2b(oa0[r] * inv);
        op[16 + lm] = f2b(oa1[r] * inv);
      }
    }
  }
}

extern "C" void kernel_launch(void* const* d_in, const int* in_sizes, int n_in,
                              void* d_out, int out_size, void* d_ws,
                              size_t ws_size, hipStream_t stream) {
  const float* x     = (const float*)d_in[0];
  const float* n1g   = (const float*)d_in[1];
  const float* n1b   = (const float*)d_in[2];
  const float* qkvw  = (const float*)d_in[3];
  const float* qkvb  = (const float*)d_in[4];
  const float* rpb   = (const float*)d_in[5];
  const float* projw = (const float*)d_in[6];
  const float* projb = (const float*)d_in[7];
  const float* n2g   = (const float*)d_in[8];
  const float* n2b   = (const float*)d_in[9];
  const float* fc1w  = (const float*)d_in[10];
  const float* fc1b  = (const float*)d_in[11];
  const float* fc2w  = (const float*)d_in[12];
  const float* fc2b  = (const float*)d_in[13];

  // Workspace (NEED = 130,547,712 B), lifetime-aliased:
  //  [0, 25.69M)            xw -> attno -> hid(low)
  //  [25.69M, 51.38M)       q            -> hid
  //  [51.38M, 77.07M)       k            -> hid
  //  [77.07M, 103.28M)      vT (26.21M)  -> hid(top)
  //  [103.28M, 123.87M)     biasB(20.48M)+rowmax(0.1M) -> h2 (25.69M)
  //  [128.97M, 130.55M)     bf16 weights (wq|wp|w1|w2 contiguous)
  // xres (fp32 residual) lives in d_out.
  const size_t NEED = 130547712;
  if (ws_size < NEED) return;

  char* ws = (char*)d_ws;
  u16* xw      = (u16*)(ws + 0LL);
  u16* qb      = (u16*)(ws + 25690112LL);
  u16* attno   = (u16*)(ws + 0LL);
  u16* hid     = (u16*)(ws + 0LL);
  u16* biasB   = (u16*)(ws + 103284736LL);
  float* rmx   = (float*)(ws + 123764736LL);
  u16* h2      = (u16*)(ws + 103284736LL);
  u16* wq      = (u16*)(ws + 128974848LL);
  u16* wp      = (u16*)(ws + 129368064LL);
  u16* w1      = (u16*)(ws + 129499136LL);
  u16* w2      = (u16*)(ws + 130023424LL);
  float* xres  = (float*)d_out;

  castw<<<3072, 256, 0, stream>>>(qkvw, projw, fc1w, fc2w, wq);
  bias_k<<<1600, 256, 0, stream>>>(rpb, biasB, rmx);

  ln_k<<<12544, 256, 0, stream>>>(x, n1g, n1b, xw, 1);
  gemm_k<0><<<196 * 6, 512, 0, stream>>>(
      xw, wq, 256, 6, qkvb, qb, nullptr, nullptr,
      0.17677669529663687f * 1.4426950408889634f);
  attn_k<<<1024, 256, 0, stream>>>(qb, qb + 12845056, qb + 2 * 12845056, biasB,
                                   rmx, attno);
  gemm_k<1><<<196 * 2, 512, 0, stream>>>(attno, wp, 256, 2, projb, nullptr,
                                         xres, x, 0.f);
  ln_k<<<12544, 256, 0, stream>>>(xres, n2g, n2b, h2, 0);
  gemm_k<2><<<196 * 8, 512, 0, stream>>>(h2, w1, 256, 8, fc1b, hid, nullptr,
                                         nullptr, 0.f);
  gemm_k<3><<<196 * 2, 512, 0, stream>>>(hid, w2, 1024, 2, fc2b, nullptr,
                                         (float*)d_out, xres, 0.f);
}